// Round 7
// baseline (16479.546 us; speedup 1.0000x reference)
//
#include <hip/hip_runtime.h>
#include <hip/hip_bf16.h>
#include <math.h>

#define B_  64
#define T_  512
#define I_  512
#define H_  1024
#define G4_ 4096
#define O_  512
#define TC_ 64             // time chunk
#define NCH (T_ / TC_)     // 8
#define WPG 16             // WGs per barrier group

typedef short  s16x8 __attribute__((ext_vector_type(8)));
typedef float  fx4   __attribute__((ext_vector_type(4)));
typedef float  fx8   __attribute__((ext_vector_type(8)));
typedef unsigned short u16;
typedef u16    u16x4 __attribute__((ext_vector_type(4)));
typedef unsigned long long u64t;

__device__ __forceinline__ u16 f2bf(float f){
  unsigned u = __float_as_uint(f);
  unsigned r = u + 0x7fffu + ((u >> 16) & 1u);   // RNE
  return (u16)(r >> 16);
}
__device__ __forceinline__ float bf2f(u16 s){ return __uint_as_float(((unsigned)s) << 16); }
__device__ __forceinline__ float sigm(float x){ return 1.0f / (1.0f + __expf(-x)); }
__device__ __forceinline__ float tanh_(float x){
  float ax = fabsf(x);
  float e  = __expf(2.0f * ax);
  float r  = 1.0f - 2.0f / (e + 1.0f);
  return copysignf(r, x);
}
__device__ __forceinline__ fx4 mfma(s16x8 a, s16x8 b, fx4 c){
  return __builtin_amdgcn_mfma_f32_16x16x32_bf16(a, b, c, 0, 0, 0);
}

// system-scope relaxed atomics: sc0+sc1 (bypass L1+L2, served at coherent point),
// NO cache-maintenance instructions -> cheap cross-XCD visibility.
__device__ __forceinline__ u64t aload64(const u16* p){
  return __hip_atomic_load((const u64t*)p, __ATOMIC_RELAXED, __HIP_MEMORY_SCOPE_SYSTEM);
}
__device__ __forceinline__ void astore32(u16* p, unsigned v){
  __hip_atomic_store((unsigned*)p, v, __ATOMIC_RELAXED, __HIP_MEMORY_SCOPE_SYSTEM);
}
__device__ __forceinline__ unsigned aload32(const unsigned* p){
  return __hip_atomic_load(p, __ATOMIC_RELAXED, __HIP_MEMORY_SCOPE_SYSTEM);
}
__device__ __forceinline__ unsigned afadd(unsigned* p){
  return __hip_atomic_fetch_add(p, 1u, __ATOMIC_RELAXED, __HIP_MEMORY_SCOPE_SYSTEM);
}

// ---------------- prep kernels ----------------
__global__ void cvt_hilo(const float* __restrict__ src, u16* __restrict__ hi,
                         u16* __restrict__ lo, int n4){
  int i      = blockIdx.x * blockDim.x + threadIdx.x;
  int stride = gridDim.x * blockDim.x;
  for (; i < n4; i += stride){
    fx4 v = ((const fx4*)src)[i];
    u16x4 h, l;
    #pragma unroll
    for (int k = 0; k < 4; ++k){
      u16 hh = f2bf(v[k]);
      h[k] = hh;
      l[k] = f2bf(v[k] - bf2f(hh));
    }
    ((u16x4*)hi)[i] = h;
    ((u16x4*)lo)[i] = l;
  }
}

__global__ void vadd(const float* __restrict__ a, const float* __restrict__ b,
                     float* __restrict__ o, int n){
  int i = blockIdx.x * blockDim.x + threadIdx.x;
  if (i < n) o[i] = a[i] + b[i];
}

// zero: c-states, both parities of the 4 h-exchange arrays, barrier state
__global__ void zero_init(float* cst1, float* cst2,
                          u16* x0, u16* x1, u16* x2, u16* x3, unsigned* bar){
  int i = blockIdx.x * blockDim.x + threadIdx.x;   // 65536 threads
  cst1[i] = 0.0f; cst2[i] = 0.0f;
  ((unsigned*)x0)[i] = 0u;   // 2*64*1024 u16 = 65536 u32
  ((unsigned*)x1)[i] = 0u;
  ((unsigned*)x2)[i] = 0u;
  ((unsigned*)x3)[i] = 0u;
  if (i < 2048) bar[i] = 0u;
}

// ---------------- bulk GEMM (split-bf16, 128x64 tile) ----------------
// Row r = tl*64 + b. AMODE 0: A = fp32 x at [b][c0+tl][KD]; AMODE 1: hi/lo [b*TC_+tl][KD].
// OMODE 0: xp out[((tl*4+g)*H + j)*64 + b];  OMODE 1: out[(b*T_+c0+tl)*N + n].
template<int KD, int AMODE, int OMODE>
__global__ __launch_bounds__(256)
void gemmX(const float* __restrict__ Af,
           const u16* __restrict__ Ah, const u16* __restrict__ Al,
           const u16* __restrict__ Bh, const u16* __restrict__ Bl,
           const float* __restrict__ bias,
           float* __restrict__ out, int N, int c0)
{
  __shared__ float xt[(OMODE == 0) ? 64 * 130 : 4];
  const int lane = threadIdx.x & 63;
  const int wv   = threadIdx.x >> 6;
  const int l15  = lane & 15;
  const int lhi  = lane >> 4;
  const int koff = lhi * 8;
  const int mb   = blockIdx.x * 128;
  const int nb   = blockIdx.y * 64;
  const int r0   = mb + wv * 32 + l15;

  fx4 acc[2][4] = {};
  for (int kt = 0; kt < KD / 32; ++kt){
    const int kb = kt * 32 + koff;
    s16x8 ah[2], al[2];
    #pragma unroll
    for (int mi = 0; mi < 2; ++mi){
      const int r  = r0 + mi * 16;
      const int b  = r & 63;
      const int tl = r >> 6;
      if (AMODE == 0){
        const float* p = Af + ((size_t)b * T_ + c0 + tl) * KD + kb;
        fx8 v = *reinterpret_cast<const fx8*>(p);
        #pragma unroll
        for (int i = 0; i < 8; ++i){
          u16 h = f2bf(v[i]);
          ah[mi][i] = (short)h;
          al[mi][i] = (short)f2bf(v[i] - bf2f(h));
        }
      } else {
        const size_t ao = ((size_t)b * TC_ + tl) * KD + kb;
        ah[mi] = *reinterpret_cast<const s16x8*>(Ah + ao);
        al[mi] = *reinterpret_cast<const s16x8*>(Al + ao);
      }
    }
    #pragma unroll
    for (int c = 0; c < 4; ++c){
      const size_t wo = (size_t)(nb + c * 16 + l15) * KD + kb;
      s16x8 bh = *reinterpret_cast<const s16x8*>(Bh + wo);
      s16x8 bl = *reinterpret_cast<const s16x8*>(Bl + wo);
      #pragma unroll
      for (int mi = 0; mi < 2; ++mi){
        acc[mi][c] = mfma(ah[mi], bh, acc[mi][c]);
        acc[mi][c] = mfma(ah[mi], bl, acc[mi][c]);
        acc[mi][c] = mfma(al[mi], bh, acc[mi][c]);
      }
    }
  }

  if (OMODE == 0){
    #pragma unroll
    for (int c = 0; c < 4; ++c){
      const int nloc = c * 16 + l15;
      const float bv = bias[nb + nloc];
      #pragma unroll
      for (int mi = 0; mi < 2; ++mi)
        #pragma unroll
        for (int r = 0; r < 4; ++r)
          xt[nloc * 130 + wv * 32 + mi * 16 + lhi * 4 + r] = acc[mi][c][r] + bv;
    }
    __syncthreads();
    const int mloc = threadIdx.x & 127;
    const int b    = mloc & 63;
    const int tl   = blockIdx.x * 2 + (mloc >> 6);
    #pragma unroll
    for (int it = 0; it < 32; ++it){
      const int nloc = (threadIdx.x >> 7) + it * 2;
      const int n = nb + nloc;
      const int g = n >> 10;
      const int j = n & 1023;
      out[((size_t)(tl * 4 + g) * H_ + j) * 64 + b] = xt[nloc * 130 + mloc];
    }
  } else {
    #pragma unroll
    for (int c = 0; c < 4; ++c){
      const int n = nb + c * 16 + l15;
      const float bv = bias[n];
      #pragma unroll
      for (int mi = 0; mi < 2; ++mi)
        #pragma unroll
        for (int r = 0; r < 4; ++r){
          const int m  = mb + wv * 32 + mi * 16 + lhi * 4 + r;
          const int b  = m & 63;
          const int tl = m >> 6;
          out[((size_t)b * T_ + c0 + tl) * (size_t)N + n] = acc[mi][c][r] + bv;
        }
    }
  }
}

// ---------------- two-level grid barrier (relaxed atomics only, no fences) -----
// bar: grp counters [gid*32], top counter [512], top flag [544], grp flags [1024+gid*32]
// Safety: a flag can only advance past epoch e after every member has exited e.
__device__ __forceinline__ void gbar(unsigned* bar, int gid, unsigned ep, int ngrp){
  if (afadd(&bar[gid * 32]) == WPG - 1u){
    __hip_atomic_store(&bar[gid * 32], 0u, __ATOMIC_RELAXED, __HIP_MEMORY_SCOPE_SYSTEM);
    if (afadd(&bar[512]) == (unsigned)(ngrp - 1)){
      __hip_atomic_store(&bar[512], 0u, __ATOMIC_RELAXED, __HIP_MEMORY_SCOPE_SYSTEM);
      astore32((u16*)&bar[544], ep);
    } else {
      while (aload32(&bar[544]) != ep) __builtin_amdgcn_s_sleep(1);
    }
    astore32((u16*)&bar[1024 + gid * 32], ep);
  } else {
    while (aload32(&bar[1024 + gid * 32]) != ep) __builtin_amdgcn_s_sleep(1);
  }
}

// ---------------- persistent dual-layer LSTM chunk ----------------
// mode 1: L1 only (128 WGs), 3: both (256 WGs, blocks 0-127 L1 / 128-255 L2),
// 2: L2 only. WG owns 8 hidden units (CT=2 col-tiles); 8 waves K-split K=1024;
// Whh + c register-resident for all TC_ steps. h exchange: [2][64][1024] u16
// hi/lo arrays via system-scope relaxed atomics (L2-bypass). One gbar per step.
__global__ __launch_bounds__(512)
void lstm_pd(int mode, unsigned ep0, int ngrp,
    const u16* __restrict__ W1h, const u16* __restrict__ W1l,
    const float* __restrict__ xp1, float* __restrict__ cst1,
    u16* __restrict__ hx1h, u16* __restrict__ hx1l,
    u16* __restrict__ ha1h, u16* __restrict__ ha1l,
    const u16* __restrict__ W2h, const u16* __restrict__ W2l,
    const float* __restrict__ xp2, float* __restrict__ cst2,
    u16* __restrict__ hx2h, u16* __restrict__ hx2l,
    u16* __restrict__ ha2h, u16* __restrict__ ha2l,
    unsigned* __restrict__ bar)
{
  __shared__ float red[64 * 129];
  int part, bx;
  if (mode == 3){ part = blockIdx.x >> 7; bx = blockIdx.x & 127; }
  else          { part = mode - 1;        bx = blockIdx.x; }
  const int gid = blockIdx.x >> 4;

  const u16*   Wh  = part ? W2h  : W1h;
  const u16*   Wl  = part ? W2l  : W1l;
  const float* xp  = part ? xp2  : xp1;
  float*       cst = part ? cst2 : cst1;
  u16*         hxh = part ? hx2h : hx1h;
  u16*         hxl = part ? hx2l : hx1l;
  u16*         hah = part ? ha2h : ha1h;
  u16*         hal = part ? ha2l : ha1l;

  const int tid  = threadIdx.x;
  const int lane = tid & 63;
  const int wv   = tid >> 6;
  const int l15  = lane & 15;
  const int lhi  = lane >> 4;
  const int koff = lhi * 8;
  const int jb8  = bx * 8;
  const int kb0  = wv * 128 + koff;

  // B cols: ct0 gate = l15>>3 (i,f), ct1 gate = 2+(l15>>3) (g,o); unit = l15&7
  const int wrow0 = ((l15 >> 3)    ) * H_ + jb8 + (l15 & 7);
  const int wrow1 = ((l15 >> 3) + 2) * H_ + jb8 + (l15 & 7);

  // Whh fragments -> registers for all TC_ steps
  s16x8 w0h[4], w0l[4], w1h[4], w1l[4];
  #pragma unroll
  for (int s = 0; s < 4; ++s){
    const size_t o0 = (size_t)wrow0 * H_ + kb0 + s * 32;
    const size_t o1 = (size_t)wrow1 * H_ + kb0 + s * 32;
    w0h[s] = *reinterpret_cast<const s16x8*>(Wh + o0);
    w0l[s] = *reinterpret_cast<const s16x8*>(Wl + o0);
    w1h[s] = *reinterpret_cast<const s16x8*>(Wh + o1);
    w1l[s] = *reinterpret_cast<const s16x8*>(Wl + o1);
  }

  // epilogue identity: tid<256 -> (b=eb, units j0, j0+1)
  const int eb = tid & 63;
  const int e2 = tid >> 6;              // 0..3 when tid<256
  const int j0 = jb8 + 2 * e2;
  float cva = 0.0f, cvb = 0.0f;
  if (tid < 256){
    cva = cst[(size_t)j0 * B_ + eb];
    cvb = cst[(size_t)(j0 + 1) * B_ + eb];
  }

  for (int tl = 0; tl < TC_; ++tl){
    const int par = tl & 1;
    const u16* rph = hxh + par * (64 * H_);
    const u16* rpl = hxl + par * (64 * H_);
    u16* nph = hxh + (par ^ 1) * (64 * H_);
    u16* npl = hxl + (par ^ 1) * (64 * H_);

    // xp prefetch (coalesced over b), overlaps with GEMM
    float xq0[4], xq1[4];
    if (tid < 256){
      #pragma unroll
      for (int g = 0; g < 4; ++g){
        const float* xr = xp + ((size_t)(tl * 4 + g) * H_ + j0) * 64 + eb;
        xq0[g] = xr[0];
        xq1[g] = xr[64];
      }
    }

    // ---- GEMM: h(prev) @ Whh slices, A-frags via u64 system atomics ----
    fx4 acc[4][2] = {};
    #pragma unroll
    for (int s = 0; s < 4; ++s){
      const int kb = kb0 + s * 32;
      #pragma unroll
      for (int mt = 0; mt < 4; ++mt){
        const int row = mt * 16 + l15;
        const u16* ph = rph + (size_t)row * H_ + kb;
        const u16* pl = rpl + (size_t)row * H_ + kb;
        union { u64t q[2]; s16x8 v; } ua, ul;
        ua.q[0] = aload64(ph);
        ua.q[1] = aload64(ph + 4);
        ul.q[0] = aload64(pl);
        ul.q[1] = aload64(pl + 4);
        acc[mt][0] = mfma(ua.v, w0h[s], acc[mt][0]);
        acc[mt][0] = mfma(ua.v, w0l[s], acc[mt][0]);
        acc[mt][0] = mfma(ul.v, w0h[s], acc[mt][0]);
        acc[mt][1] = mfma(ua.v, w1h[s], acc[mt][1]);
        acc[mt][1] = mfma(ua.v, w1l[s], acc[mt][1]);
        acc[mt][1] = mfma(ul.v, w1h[s], acc[mt][1]);
      }
    }

    // ---- phase A reduce: ct0 (i,f) ----
    #pragma unroll
    for (int mt = 0; mt < 4; ++mt)
      #pragma unroll
      for (int r = 0; r < 4; ++r)
        red[(mt * 16 + lhi * 4 + r) * 129 + l15 * 8 + wv] = acc[mt][0][r];
    __syncthreads();
    float i0s = 0, i1s = 0, f0s = 0, f1s = 0;
    if (tid < 256){
      const float* r0 = red + eb * 129 + (2 * e2) * 8;
      const float* r1 = red + eb * 129 + (2 * e2 + 1) * 8;
      const float* r2 = red + eb * 129 + (8 + 2 * e2) * 8;
      const float* r3 = red + eb * 129 + (8 + 2 * e2 + 1) * 8;
      #pragma unroll
      for (int w = 0; w < 8; ++w){
        i0s += r0[w]; i1s += r1[w]; f0s += r2[w]; f1s += r3[w];
      }
    }
    __syncthreads();

    // ---- phase B reduce: ct1 (g,o) ----
    #pragma unroll
    for (int mt = 0; mt < 4; ++mt)
      #pragma unroll
      for (int r = 0; r < 4; ++r)
        red[(mt * 16 + lhi * 4 + r) * 129 + l15 * 8 + wv] = acc[mt][1][r];
    __syncthreads();

    if (tid < 256){
      float g0s = 0, g1s = 0, o0s = 0, o1s = 0;
      const float* r0 = red + eb * 129 + (2 * e2) * 8;
      const float* r1 = red + eb * 129 + (2 * e2 + 1) * 8;
      const float* r2 = red + eb * 129 + (8 + 2 * e2) * 8;
      const float* r3 = red + eb * 129 + (8 + 2 * e2 + 1) * 8;
      #pragma unroll
      for (int w = 0; w < 8; ++w){
        g0s += r0[w]; g1s += r1[w]; o0s += r2[w]; o1s += r3[w];
      }
      // unit j0
      float iv = sigm (i0s + xq0[0]);
      float fv = sigm (f0s + xq0[1]);
      float gv = tanh_(g0s + xq0[2]);
      float ov = sigm (o0s + xq0[3]);
      float cn = fv * cva + iv * gv;
      float h0 = ov * tanh_(cn);
      cva = cn;
      // unit j0+1
      iv = sigm (i1s + xq1[0]);
      fv = sigm (f1s + xq1[1]);
      gv = tanh_(g1s + xq1[2]);
      ov = sigm (o1s + xq1[3]);
      cn = fv * cvb + iv * gv;
      float h1 = ov * tanh_(cn);
      cvb = cn;

      u16 h0h = f2bf(h0), h0l = f2bf(h0 - bf2f(h0h));
      u16 h1h = f2bf(h1), h1l = f2bf(h1 - bf2f(h1h));
      // h exchange: packed u32 system atomics (L2-bypass)
      astore32(nph + (size_t)eb * H_ + j0, (unsigned)h0h | ((unsigned)h1h << 16));
      astore32(npl + (size_t)eb * H_ + j0, (unsigned)h0l | ((unsigned)h1l << 16));
      // archive: normal u32 stores (read by later gemmX after kernel end)
      const size_t ai = ((size_t)eb * TC_ + tl) * H_ + j0;
      *(unsigned*)(hah + ai) = (unsigned)h0h | ((unsigned)h1h << 16);
      *(unsigned*)(hal + ai) = (unsigned)h0l | ((unsigned)h1l << 16);
    }

    __syncthreads();                    // drains vmcnt: h stores acked at L3
    if (tid == 0) gbar(bar, gid, ep0 + tl + 1, ngrp);
    __syncthreads();
  }
  if (tid < 256){
    cst[(size_t)j0 * B_ + eb]       = cva;
    cst[(size_t)(j0 + 1) * B_ + eb] = cvb;
  }
}

// ---------------- host launch ----------------
extern "C" void kernel_launch(void* const* d_in, const int* in_sizes, int n_in,
                              void* d_out, int out_size, void* d_ws, size_t ws_size,
                              hipStream_t stream)
{
  const float* x    = (const float*)d_in[0];
  const float* Wih1 = (const float*)d_in[1];
  const float* Whh1 = (const float*)d_in[2];
  const float* bih1 = (const float*)d_in[3];
  const float* bhh1 = (const float*)d_in[4];
  const float* Wih2 = (const float*)d_in[5];
  const float* Whh2 = (const float*)d_in[6];
  const float* bih2 = (const float*)d_in[7];
  const float* bhh2 = (const float*)d_in[8];
  const float* fcW  = (const float*)d_in[9];
  const float* fcb  = (const float*)d_in[10];
  float* out = (float*)d_out;
  (void)in_sizes; (void)n_in; (void)out_size; (void)ws_size;

  char* base = (char*)d_ws;
  size_t off = 0;
  auto alloc = [&](size_t bytes) -> void* {
    void* p = base + off;
    off = (off + bytes + 255) & ~(size_t)255;
    return p;
  };
  u16* Wih1_hi = (u16*)alloc((size_t)G4_ * I_ * 2);
  u16* Wih1_lo = (u16*)alloc((size_t)G4_ * I_ * 2);
  u16* Whh1_hi = (u16*)alloc((size_t)G4_ * H_ * 2);
  u16* Whh1_lo = (u16*)alloc((size_t)G4_ * H_ * 2);
  u16* Wih2_hi = (u16*)alloc((size_t)G4_ * H_ * 2);
  u16* Wih2_lo = (u16*)alloc((size_t)G4_ * H_ * 2);
  u16* Whh2_hi = (u16*)alloc((size_t)G4_ * H_ * 2);
  u16* Whh2_lo = (u16*)alloc((size_t)G4_ * H_ * 2);
  u16* fcW_hi  = (u16*)alloc((size_t)O_ * H_ * 2);
  u16* fcW_lo  = (u16*)alloc((size_t)O_ * H_ * 2);
  float* bsum1 = (float*)alloc((size_t)G4_ * 4);
  float* bsum2 = (float*)alloc((size_t)G4_ * 4);
  float* cst1  = (float*)alloc((size_t)B_ * H_ * 4);
  float* cst2  = (float*)alloc((size_t)B_ * H_ * 4);
  u16* hx1h = (u16*)alloc((size_t)2 * B_ * H_ * 2);   // [2][64][1024] exchange
  u16* hx1l = (u16*)alloc((size_t)2 * B_ * H_ * 2);
  u16* hx2h = (u16*)alloc((size_t)2 * B_ * H_ * 2);
  u16* hx2l = (u16*)alloc((size_t)2 * B_ * H_ * 2);
  u16* h1s_hi = (u16*)alloc((size_t)B_ * TC_ * H_ * 2);
  u16* h1s_lo = (u16*)alloc((size_t)B_ * TC_ * H_ * 2);
  u16* h2s_hi = (u16*)alloc((size_t)B_ * TC_ * H_ * 2);
  u16* h2s_lo = (u16*)alloc((size_t)B_ * TC_ * H_ * 2);
  float* xp1  = (float*)alloc((size_t)TC_ * G4_ * B_ * 4);  // 64 MB, [tl][g][j][b]
  float* xp2  = (float*)alloc((size_t)TC_ * G4_ * B_ * 4);  // 64 MB
  unsigned* bar = (unsigned*)alloc(2048 * 4);

  // ---- prep ----
  cvt_hilo<<<512, 256, 0, stream>>>(Wih1, Wih1_hi, Wih1_lo, G4_ * I_ / 4);
  cvt_hilo<<<512, 256, 0, stream>>>(Whh1, Whh1_hi, Whh1_lo, G4_ * H_ / 4);
  cvt_hilo<<<512, 256, 0, stream>>>(Wih2, Wih2_hi, Wih2_lo, G4_ * H_ / 4);
  cvt_hilo<<<512, 256, 0, stream>>>(Whh2, Whh2_hi, Whh2_lo, G4_ * H_ / 4);
  cvt_hilo<<<256, 256, 0, stream>>>(fcW,  fcW_hi,  fcW_lo,  O_ * H_ / 4);
  vadd<<<16, 256, 0, stream>>>(bih1, bhh1, bsum1, G4_);
  vadd<<<16, 256, 0, stream>>>(bih2, bhh2, bsum2, G4_);
  zero_init<<<256, 256, 0, stream>>>(cst1, cst2, hx1h, hx1l, hx2h, hx2l, bar);

  const dim3 gX(32, 64);   // M=4096/128, N=4096/64
  const dim3 gF(32, 8);

  // xp1 for chunk 0
  gemmX<I_, 0, 0><<<gX, 256, 0, stream>>>(
      x, nullptr, nullptr, Wih1_hi, Wih1_lo, bsum1, xp1, G4_, 0);

  unsigned ep = 0;
  for (int c = 0; c <= NCH; ++c){
    const int mode = ((c < NCH) ? 1 : 0) | ((c >= 1) ? 2 : 0);
    const int nwg  = (mode == 3) ? 256 : 128;
    int ngrp = nwg / WPG;
    {
      void* args[] = { (void*)&mode, (void*)&ep, (void*)&ngrp,
                       (void*)&Whh1_hi, (void*)&Whh1_lo, (void*)&xp1, (void*)&cst1,
                       (void*)&hx1h, (void*)&hx1l, (void*)&h1s_hi, (void*)&h1s_lo,
                       (void*)&Whh2_hi, (void*)&Whh2_lo, (void*)&xp2, (void*)&cst2,
                       (void*)&hx2h, (void*)&hx2l, (void*)&h2s_hi, (void*)&h2s_lo,
                       (void*)&bar };
      hipLaunchCooperativeKernel((const void*)lstm_pd, dim3(nwg), dim3(512),
                                 args, 0, stream);
      ep += TC_;
    }
    if (c < NCH)
      gemmX<H_, 1, 0><<<gX, 256, 0, stream>>>(
          nullptr, h1s_hi, h1s_lo, Wih2_hi, Wih2_lo, bsum2, xp2, G4_, 0);
    if (c + 1 < NCH)
      gemmX<I_, 0, 0><<<gX, 256, 0, stream>>>(
          x, nullptr, nullptr, Wih1_hi, Wih1_lo, bsum1, xp1, G4_, (c + 1) * TC_);
    if (c >= 1)
      gemmX<H_, 1, 1><<<gF, 256, 0, stream>>>(
          nullptr, h2s_hi, h2s_lo, fcW_hi, fcW_lo, fcb, out, O_, (c - 1) * TC_);
  }
}

// Round 8
// 13841.432 us; speedup vs baseline: 1.1906x; 1.1906x over previous
//
#include <hip/hip_runtime.h>
#include <hip/hip_bf16.h>
#include <math.h>

#define B_  64
#define T_  512
#define I_  512
#define H_  1024
#define G4_ 4096
#define O_  512
#define TC_ 64             // time chunk
#define NCH (T_ / TC_)     // 8
#define WPG 16             // WGs per barrier group

typedef short  s16x8 __attribute__((ext_vector_type(8)));
typedef float  fx4   __attribute__((ext_vector_type(4)));
typedef float  fx8   __attribute__((ext_vector_type(8)));
typedef unsigned short u16;
typedef u16    u16x4 __attribute__((ext_vector_type(4)));
typedef unsigned long long u64t;

__device__ __forceinline__ u16 f2bf(float f){
  unsigned u = __float_as_uint(f);
  unsigned r = u + 0x7fffu + ((u >> 16) & 1u);   // RNE
  return (u16)(r >> 16);
}
__device__ __forceinline__ float bf2f(u16 s){ return __uint_as_float(((unsigned)s) << 16); }
__device__ __forceinline__ float sigm(float x){ return 1.0f / (1.0f + __expf(-x)); }
__device__ __forceinline__ float tanh_(float x){
  float ax = fabsf(x);
  float e  = __expf(2.0f * ax);
  float r  = 1.0f - 2.0f / (e + 1.0f);
  return copysignf(r, x);
}
__device__ __forceinline__ fx4 mfma(s16x8 a, s16x8 b, fx4 c){
  return __builtin_amdgcn_mfma_f32_16x16x32_bf16(a, b, c, 0, 0, 0);
}

// system-scope relaxed atomics: cache-bypass, no cache-maintenance instructions
__device__ __forceinline__ u64t aload64(const u16* p){
  return __hip_atomic_load((const u64t*)p, __ATOMIC_RELAXED, __HIP_MEMORY_SCOPE_SYSTEM);
}
__device__ __forceinline__ void astore32(u16* p, unsigned v){
  __hip_atomic_store((unsigned*)p, v, __ATOMIC_RELAXED, __HIP_MEMORY_SCOPE_SYSTEM);
}
__device__ __forceinline__ unsigned aload32(const unsigned* p){
  return __hip_atomic_load(p, __ATOMIC_RELAXED, __HIP_MEMORY_SCOPE_SYSTEM);
}
__device__ __forceinline__ unsigned afadd(unsigned* p){
  return __hip_atomic_fetch_add(p, 1u, __ATOMIC_RELAXED, __HIP_MEMORY_SCOPE_SYSTEM);
}

// ---------------- prep kernels ----------------
__global__ void cvt_hilo(const float* __restrict__ src, u16* __restrict__ hi,
                         u16* __restrict__ lo, int n4){
  int i      = blockIdx.x * blockDim.x + threadIdx.x;
  int stride = gridDim.x * blockDim.x;
  for (; i < n4; i += stride){
    fx4 v = ((const fx4*)src)[i];
    u16x4 h, l;
    #pragma unroll
    for (int k = 0; k < 4; ++k){
      u16 hh = f2bf(v[k]);
      h[k] = hh;
      l[k] = f2bf(v[k] - bf2f(hh));
    }
    ((u16x4*)hi)[i] = h;
    ((u16x4*)lo)[i] = l;
  }
}

__global__ void vadd(const float* __restrict__ a, const float* __restrict__ b,
                     float* __restrict__ o, int n){
  int i = blockIdx.x * blockDim.x + threadIdx.x;
  if (i < n) o[i] = a[i] + b[i];
}

__global__ void zero_init(float* cst1, float* cst2,
                          u16* x0, u16* x1, u16* x2, u16* x3, unsigned* bar){
  int i = blockIdx.x * blockDim.x + threadIdx.x;   // 65536 threads
  cst1[i] = 0.0f; cst2[i] = 0.0f;
  ((unsigned*)x0)[i] = 0u;
  ((unsigned*)x1)[i] = 0u;
  ((unsigned*)x2)[i] = 0u;
  ((unsigned*)x3)[i] = 0u;
  if (i < 2048) bar[i] = 0u;
}

// ---------------- bulk GEMM (split-bf16, 128x64 tile) ----------------
template<int KD, int AMODE, int OMODE>
__global__ __launch_bounds__(256)
void gemmX(const float* __restrict__ Af,
           const u16* __restrict__ Ah, const u16* __restrict__ Al,
           const u16* __restrict__ Bh, const u16* __restrict__ Bl,
           const float* __restrict__ bias,
           float* __restrict__ out, int N, int c0)
{
  __shared__ float xt[(OMODE == 0) ? 64 * 130 : 4];
  const int lane = threadIdx.x & 63;
  const int wv   = threadIdx.x >> 6;
  const int l15  = lane & 15;
  const int lhi  = lane >> 4;
  const int koff = lhi * 8;
  const int mb   = blockIdx.x * 128;
  const int nb   = blockIdx.y * 64;
  const int r0   = mb + wv * 32 + l15;

  fx4 acc[2][4] = {};
  for (int kt = 0; kt < KD / 32; ++kt){
    const int kb = kt * 32 + koff;
    s16x8 ah[2], al[2];
    #pragma unroll
    for (int mi = 0; mi < 2; ++mi){
      const int r  = r0 + mi * 16;
      const int b  = r & 63;
      const int tl = r >> 6;
      if (AMODE == 0){
        const float* p = Af + ((size_t)b * T_ + c0 + tl) * KD + kb;
        fx8 v = *reinterpret_cast<const fx8*>(p);
        #pragma unroll
        for (int i = 0; i < 8; ++i){
          u16 h = f2bf(v[i]);
          ah[mi][i] = (short)h;
          al[mi][i] = (short)f2bf(v[i] - bf2f(h));
        }
      } else {
        const size_t ao = ((size_t)b * TC_ + tl) * KD + kb;
        ah[mi] = *reinterpret_cast<const s16x8*>(Ah + ao);
        al[mi] = *reinterpret_cast<const s16x8*>(Al + ao);
      }
    }
    #pragma unroll
    for (int c = 0; c < 4; ++c){
      const size_t wo = (size_t)(nb + c * 16 + l15) * KD + kb;
      s16x8 bh = *reinterpret_cast<const s16x8*>(Bh + wo);
      s16x8 bl = *reinterpret_cast<const s16x8*>(Bl + wo);
      #pragma unroll
      for (int mi = 0; mi < 2; ++mi){
        acc[mi][c] = mfma(ah[mi], bh, acc[mi][c]);
        acc[mi][c] = mfma(ah[mi], bl, acc[mi][c]);
        acc[mi][c] = mfma(al[mi], bh, acc[mi][c]);
      }
    }
  }

  if (OMODE == 0){
    #pragma unroll
    for (int c = 0; c < 4; ++c){
      const int nloc = c * 16 + l15;
      const float bv = bias[nb + nloc];
      #pragma unroll
      for (int mi = 0; mi < 2; ++mi)
        #pragma unroll
        for (int r = 0; r < 4; ++r)
          xt[nloc * 130 + wv * 32 + mi * 16 + lhi * 4 + r] = acc[mi][c][r] + bv;
    }
    __syncthreads();
    const int mloc = threadIdx.x & 127;
    const int b    = mloc & 63;
    const int tl   = blockIdx.x * 2 + (mloc >> 6);
    #pragma unroll
    for (int it = 0; it < 32; ++it){
      const int nloc = (threadIdx.x >> 7) + it * 2;
      const int n = nb + nloc;
      const int g = n >> 10;
      const int j = n & 1023;
      out[((size_t)(tl * 4 + g) * H_ + j) * 64 + b] = xt[nloc * 130 + mloc];
    }
  } else {
    #pragma unroll
    for (int c = 0; c < 4; ++c){
      const int n = nb + c * 16 + l15;
      const float bv = bias[n];
      #pragma unroll
      for (int mi = 0; mi < 2; ++mi)
        #pragma unroll
        for (int r = 0; r < 4; ++r){
          const int m  = mb + wv * 32 + mi * 16 + lhi * 4 + r;
          const int b  = m & 63;
          const int tl = m >> 6;
          out[((size_t)b * T_ + c0 + tl) * (size_t)N + n] = acc[mi][c][r] + bv;
        }
    }
  }
}

// ---------------- two-level grid barrier (relaxed atomics, no fences) ----------
__device__ __forceinline__ void gbar(unsigned* bar, int gid, unsigned ep, int ngrp){
  if (afadd(&bar[gid * 32]) == WPG - 1u){
    __hip_atomic_store(&bar[gid * 32], 0u, __ATOMIC_RELAXED, __HIP_MEMORY_SCOPE_SYSTEM);
    if (afadd(&bar[512]) == (unsigned)(ngrp - 1)){
      __hip_atomic_store(&bar[512], 0u, __ATOMIC_RELAXED, __HIP_MEMORY_SCOPE_SYSTEM);
      astore32((u16*)&bar[544], ep);
    } else {
      while (aload32(&bar[544]) != ep) __builtin_amdgcn_s_sleep(1);
    }
    astore32((u16*)&bar[1024 + gid * 32], ep);
  } else {
    while (aload32(&bar[1024 + gid * 32]) != ep) __builtin_amdgcn_s_sleep(1);
  }
}

// ---------------- persistent dual-layer LSTM chunk (low-broadcast decomposition)
// Grid: mode3 = 256 WGs (2 layers x 4 M-tiles x 32 unit-groups), else 128.
// blockIdx mapping is XCD-pinned: idx&7 = XCD slot; all WGs sharing a W slice
// (same unit-group) land on one XCD so streamed W stays L2-resident.
// WG = (layer, M-tile of 16 batch rows, 32 units x 4 gates = 128 gate-cols).
// 8 waves K-split K=1024 (128 each). W gates {i,f} (coltiles 0-3) register-
// resident for the whole chunk; gates {g,o} (coltiles 4-7) streamed from L2.
// h read = only 16 rows/WG -> 16 MB/step total broadcast (4x less than r7).
__global__ __launch_bounds__(512)
void lstm_pd(int mode, unsigned ep0, int ngrp,
    const u16* __restrict__ W1h, const u16* __restrict__ W1l,
    const float* __restrict__ xp1, float* __restrict__ cst1,
    u16* __restrict__ hx1h, u16* __restrict__ hx1l,
    u16* __restrict__ ha1h, u16* __restrict__ ha1l,
    const u16* __restrict__ W2h, const u16* __restrict__ W2l,
    const float* __restrict__ xp2, float* __restrict__ cst2,
    u16* __restrict__ hx2h, u16* __restrict__ hx2l,
    u16* __restrict__ ha2h, u16* __restrict__ ha2l,
    unsigned* __restrict__ bar)
{
  __shared__ float red[16 * 521 + 8];

  const int x8 = blockIdx.x & 7;
  const int q  = blockIdx.x >> 3;
  int part, m4, ghi;
  if (mode == 3){ part = q & 1;    m4 = (q >> 1) & 3; ghi = q >> 3; }
  else          { part = mode - 1; m4 = q & 3;        ghi = q >> 2; }
  const int jb  = (x8 + 8 * ghi) * 32;    // unit base (0..992)
  const int mb  = m4 * 16;                // batch-row base
  const int gid = blockIdx.x >> 4;

  const u16*   Wh  = part ? W2h  : W1h;
  const u16*   Wl  = part ? W2l  : W1l;
  const float* xp  = part ? xp2  : xp1;
  float*       cst = part ? cst2 : cst1;
  u16*         hxh = part ? hx2h : hx1h;
  u16*         hxl = part ? hx2l : hx1l;
  u16*         hah = part ? ha2h : ha1h;
  u16*         hal = part ? ha2l : ha1l;

  const int tid  = threadIdx.x;
  const int lane = tid & 63;
  const int wv   = tid >> 6;              // 0..7 = K slice
  const int l15  = lane & 15;
  const int lhi  = lane >> 4;
  const int kb0  = wv * 128 + lhi * 8;

  // W row (= gate-col) for coltile ct, lane l15: cl = ct*16+l15; gate = cl>>5
  size_t wrowR[4], wrowS[4];
  #pragma unroll
  for (int ct = 0; ct < 4; ++ct){
    const int clR = ct * 16 + l15;
    const int clS = (ct + 4) * 16 + l15;
    wrowR[ct] = (size_t)((clR >> 5) * H_ + jb + (clR & 31));
    wrowS[ct] = (size_t)((clS >> 5) * H_ + jb + (clS & 31));
  }

  // register-resident W for gates i,f (coltiles 0-3), whole chunk
  s16x8 wrh[4][4], wrl[4][4];
  #pragma unroll
  for (int ct = 0; ct < 4; ++ct)
    #pragma unroll
    for (int s = 0; s < 4; ++s){
      const size_t wo = wrowR[ct] * H_ + kb0 + s * 32;
      wrh[ct][s] = *reinterpret_cast<const s16x8*>(Wh + wo);
      wrl[ct][s] = *reinterpret_cast<const s16x8*>(Wl + wo);
    }

  // epilogue identity: tid<256 -> (batch row b, unit pair u0,u0+1)
  const int up = tid & 15;                // unit pair
  const int mm = tid >> 4;                // row within tile (0..15)
  const int u0 = 2 * up;
  const int j0 = jb + u0;
  const int eb = mb + mm;
  float cva = 0.0f, cvb = 0.0f;
  if (tid < 256){
    cva = cst[(size_t)j0 * B_ + eb];
    cvb = cst[(size_t)(j0 + 1) * B_ + eb];
  }

  for (int tl = 0; tl < TC_; ++tl){
    const int par = tl & 1;
    const u16* rph = hxh + par * (64 * H_);
    const u16* rpl = hxl + par * (64 * H_);
    u16* nph = hxh + (par ^ 1) * (64 * H_);
    u16* npl = hxl + (par ^ 1) * (64 * H_);

    // xp prefetch (overlaps GEMM)
    float xq0[4], xq1[4];
    if (tid < 256){
      #pragma unroll
      for (int g = 0; g < 4; ++g){
        const float* xr = xp + ((size_t)(tl * 4 + g) * H_ + j0) * 64 + eb;
        xq0[g] = xr[0];
        xq1[g] = xr[64];
      }
    }

    // ---- GEMM: h[16 rows] x W[128 cols], K-slice per wave ----
    fx4 acc[8] = {};
    #pragma unroll
    for (int s = 0; s < 4; ++s){
      const int kb = kb0 + s * 32;
      const u16* ph = rph + (size_t)(mb + l15) * H_ + kb;
      const u16* pl = rpl + (size_t)(mb + l15) * H_ + kb;
      union { u64t u[2]; s16x8 v; } ua, ul;
      ua.u[0] = aload64(ph);  ua.u[1] = aload64(ph + 4);
      ul.u[0] = aload64(pl);  ul.u[1] = aload64(pl + 4);
      #pragma unroll
      for (int ct = 0; ct < 4; ++ct){
        acc[ct] = mfma(ua.v, wrh[ct][s], acc[ct]);
        acc[ct] = mfma(ua.v, wrl[ct][s], acc[ct]);
        acc[ct] = mfma(ul.v, wrh[ct][s], acc[ct]);
      }
      #pragma unroll
      for (int ct = 0; ct < 4; ++ct){
        const size_t wo = wrowS[ct] * H_ + kb;
        s16x8 bh = *reinterpret_cast<const s16x8*>(Wh + wo);
        s16x8 bl = *reinterpret_cast<const s16x8*>(Wl + wo);
        acc[4 + ct] = mfma(ua.v, bh, acc[4 + ct]);
        acc[4 + ct] = mfma(ua.v, bl, acc[4 + ct]);
        acc[4 + ct] = mfma(ul.v, bh, acc[4 + ct]);
      }
    }

    // ---- phase A reduce: coltiles 0-3 (gates i,f) ----
    // D layout: col = l15 (->clL = ct*16+l15), row = lhi*4+r (batch row in tile)
    #pragma unroll
    for (int ct = 0; ct < 4; ++ct)
      #pragma unroll
      for (int r = 0; r < 4; ++r)
        red[(lhi * 4 + r) * 521 + (ct * 16 + l15) * 8 + wv] = acc[ct][r];
    __syncthreads();
    float i0s = 0, i1s = 0, f0s = 0, f1s = 0;
    if (tid < 256){
      const float* r0 = red + mm * 521 + (u0) * 8;          // gate i, unit u0
      const float* r1 = red + mm * 521 + (u0 + 1) * 8;      // gate i, unit u0+1
      const float* r2 = red + mm * 521 + (32 + u0) * 8;     // gate f, unit u0
      const float* r3 = red + mm * 521 + (32 + u0 + 1) * 8; // gate f, unit u0+1
      #pragma unroll
      for (int w = 0; w < 8; ++w){
        i0s += r0[w]; i1s += r1[w]; f0s += r2[w]; f1s += r3[w];
      }
    }
    __syncthreads();

    // ---- phase B reduce: coltiles 4-7 (gates g,o) ----
    #pragma unroll
    for (int ct = 0; ct < 4; ++ct)
      #pragma unroll
      for (int r = 0; r < 4; ++r)
        red[(lhi * 4 + r) * 521 + (ct * 16 + l15) * 8 + wv] = acc[4 + ct][r];
    __syncthreads();

    if (tid < 256){
      float g0s = 0, g1s = 0, o0s = 0, o1s = 0;
      const float* r0 = red + mm * 521 + (u0) * 8;
      const float* r1 = red + mm * 521 + (u0 + 1) * 8;
      const float* r2 = red + mm * 521 + (32 + u0) * 8;
      const float* r3 = red + mm * 521 + (32 + u0 + 1) * 8;
      #pragma unroll
      for (int w = 0; w < 8; ++w){
        g0s += r0[w]; g1s += r1[w]; o0s += r2[w]; o1s += r3[w];
      }
      // unit j0
      float iv = sigm (i0s + xq0[0]);
      float fv = sigm (f0s + xq0[1]);
      float gv = tanh_(g0s + xq0[2]);
      float ov = sigm (o0s + xq0[3]);
      float cn = fv * cva + iv * gv;
      float h0 = ov * tanh_(cn);
      cva = cn;
      // unit j0+1
      iv = sigm (i1s + xq1[0]);
      fv = sigm (f1s + xq1[1]);
      gv = tanh_(g1s + xq1[2]);
      ov = sigm (o1s + xq1[3]);
      cn = fv * cvb + iv * gv;
      float h1 = ov * tanh_(cn);
      cvb = cn;

      u16 h0h = f2bf(h0), h0l = f2bf(h0 - bf2f(h0h));
      u16 h1h = f2bf(h1), h1l = f2bf(h1 - bf2f(h1h));
      astore32(nph + (size_t)eb * H_ + j0, (unsigned)h0h | ((unsigned)h1h << 16));
      astore32(npl + (size_t)eb * H_ + j0, (unsigned)h0l | ((unsigned)h1l << 16));
      const size_t ai = ((size_t)eb * TC_ + tl) * H_ + j0;
      *(unsigned*)(hah + ai) = (unsigned)h0h | ((unsigned)h1h << 16);
      *(unsigned*)(hal + ai) = (unsigned)h0l | ((unsigned)h1l << 16);
    }

    __syncthreads();                      // drains vmcnt before signal
    if (tid == 0) gbar(bar, gid, ep0 + tl + 1, ngrp);
    __syncthreads();
  }
  if (tid < 256){
    cst[(size_t)j0 * B_ + eb]       = cva;
    cst[(size_t)(j0 + 1) * B_ + eb] = cvb;
  }
}

// ---------------- host launch ----------------
extern "C" void kernel_launch(void* const* d_in, const int* in_sizes, int n_in,
                              void* d_out, int out_size, void* d_ws, size_t ws_size,
                              hipStream_t stream)
{
  const float* x    = (const float*)d_in[0];
  const float* Wih1 = (const float*)d_in[1];
  const float* Whh1 = (const float*)d_in[2];
  const float* bih1 = (const float*)d_in[3];
  const float* bhh1 = (const float*)d_in[4];
  const float* Wih2 = (const float*)d_in[5];
  const float* Whh2 = (const float*)d_in[6];
  const float* bih2 = (const float*)d_in[7];
  const float* bhh2 = (const float*)d_in[8];
  const float* fcW  = (const float*)d_in[9];
  const float* fcb  = (const float*)d_in[10];
  float* out = (float*)d_out;
  (void)in_sizes; (void)n_in; (void)out_size; (void)ws_size;

  char* base = (char*)d_ws;
  size_t off = 0;
  auto alloc = [&](size_t bytes) -> void* {
    void* p = base + off;
    off = (off + bytes + 255) & ~(size_t)255;
    return p;
  };
  u16* Wih1_hi = (u16*)alloc((size_t)G4_ * I_ * 2);
  u16* Wih1_lo = (u16*)alloc((size_t)G4_ * I_ * 2);
  u16* Whh1_hi = (u16*)alloc((size_t)G4_ * H_ * 2);
  u16* Whh1_lo = (u16*)alloc((size_t)G4_ * H_ * 2);
  u16* Wih2_hi = (u16*)alloc((size_t)G4_ * H_ * 2);
  u16* Wih2_lo = (u16*)alloc((size_t)G4_ * H_ * 2);
  u16* Whh2_hi = (u16*)alloc((size_t)G4_ * H_ * 2);
  u16* Whh2_lo = (u16*)alloc((size_t)G4_ * H_ * 2);
  u16* fcW_hi  = (u16*)alloc((size_t)O_ * H_ * 2);
  u16* fcW_lo  = (u16*)alloc((size_t)O_ * H_ * 2);
  float* bsum1 = (float*)alloc((size_t)G4_ * 4);
  float* bsum2 = (float*)alloc((size_t)G4_ * 4);
  float* cst1  = (float*)alloc((size_t)B_ * H_ * 4);
  float* cst2  = (float*)alloc((size_t)B_ * H_ * 4);
  u16* hx1h = (u16*)alloc((size_t)2 * B_ * H_ * 2);
  u16* hx1l = (u16*)alloc((size_t)2 * B_ * H_ * 2);
  u16* hx2h = (u16*)alloc((size_t)2 * B_ * H_ * 2);
  u16* hx2l = (u16*)alloc((size_t)2 * B_ * H_ * 2);
  u16* h1s_hi = (u16*)alloc((size_t)B_ * TC_ * H_ * 2);
  u16* h1s_lo = (u16*)alloc((size_t)B_ * TC_ * H_ * 2);
  u16* h2s_hi = (u16*)alloc((size_t)B_ * TC_ * H_ * 2);
  u16* h2s_lo = (u16*)alloc((size_t)B_ * TC_ * H_ * 2);
  float* xp1  = (float*)alloc((size_t)TC_ * G4_ * B_ * 4);
  float* xp2  = (float*)alloc((size_t)TC_ * G4_ * B_ * 4);
  unsigned* bar = (unsigned*)alloc(2048 * 4);

  // ---- prep ----
  cvt_hilo<<<512, 256, 0, stream>>>(Wih1, Wih1_hi, Wih1_lo, G4_ * I_ / 4);
  cvt_hilo<<<512, 256, 0, stream>>>(Whh1, Whh1_hi, Whh1_lo, G4_ * H_ / 4);
  cvt_hilo<<<512, 256, 0, stream>>>(Wih2, Wih2_hi, Wih2_lo, G4_ * H_ / 4);
  cvt_hilo<<<512, 256, 0, stream>>>(Whh2, Whh2_hi, Whh2_lo, G4_ * H_ / 4);
  cvt_hilo<<<256, 256, 0, stream>>>(fcW,  fcW_hi,  fcW_lo,  O_ * H_ / 4);
  vadd<<<16, 256, 0, stream>>>(bih1, bhh1, bsum1, G4_);
  vadd<<<16, 256, 0, stream>>>(bih2, bhh2, bsum2, G4_);
  zero_init<<<256, 256, 0, stream>>>(cst1, cst2, hx1h, hx1l, hx2h, hx2l, bar);

  const dim3 gX(32, 64);
  const dim3 gF(32, 8);

  gemmX<I_, 0, 0><<<gX, 256, 0, stream>>>(
      x, nullptr, nullptr, Wih1_hi, Wih1_lo, bsum1, xp1, G4_, 0);

  unsigned ep = 0;
  for (int c = 0; c <= NCH; ++c){
    const int mode = ((c < NCH) ? 1 : 0) | ((c >= 1) ? 2 : 0);
    const int nwg  = (mode == 3) ? 256 : 128;
    int ngrp = nwg / WPG;
    {
      void* args[] = { (void*)&mode, (void*)&ep, (void*)&ngrp,
                       (void*)&Whh1_hi, (void*)&Whh1_lo, (void*)&xp1, (void*)&cst1,
                       (void*)&hx1h, (void*)&hx1l, (void*)&h1s_hi, (void*)&h1s_lo,
                       (void*)&Whh2_hi, (void*)&Whh2_lo, (void*)&xp2, (void*)&cst2,
                       (void*)&hx2h, (void*)&hx2l, (void*)&h2s_hi, (void*)&h2s_lo,
                       (void*)&bar };
      hipLaunchCooperativeKernel((const void*)lstm_pd, dim3(nwg), dim3(512),
                                 args, 0, stream);
      ep += TC_;
    }
    if (c < NCH)
      gemmX<H_, 1, 0><<<gX, 256, 0, stream>>>(
          nullptr, h1s_hi, h1s_lo, Wih2_hi, Wih2_lo, bsum2, xp2, G4_, 0);
    if (c + 1 < NCH)
      gemmX<I_, 0, 0><<<gX, 256, 0, stream>>>(
          x, nullptr, nullptr, Wih1_hi, Wih1_lo, bsum1, xp1, G4_, (c + 1) * TC_);
    if (c >= 1)
      gemmX<H_, 1, 1><<<gF, 256, 0, stream>>>(
          nullptr, h2s_hi, h2s_lo, fcW_hi, fcW_lo, fcb, out, O_, (c - 1) * TC_);
  }
}

// Round 9
// 13282.697 us; speedup vs baseline: 1.2407x; 1.0421x over previous
//
#include <hip/hip_runtime.h>
#include <hip/hip_bf16.h>
#include <math.h>

#define B_  64
#define T_  512
#define I_  512
#define H_  1024
#define G4_ 4096
#define O_  512
#define TC_ 64             // time chunk
#define NCH (T_ / TC_)     // 8
#define WPG 16             // WGs per barrier group

typedef short  s16x8 __attribute__((ext_vector_type(8)));
typedef float  fx4   __attribute__((ext_vector_type(4)));
typedef float  fx8   __attribute__((ext_vector_type(8)));
typedef unsigned short u16;
typedef u16    u16x4 __attribute__((ext_vector_type(4)));
typedef unsigned long long u64t;

__device__ __forceinline__ u16 f2bf(float f){
  unsigned u = __float_as_uint(f);
  unsigned r = u + 0x7fffu + ((u >> 16) & 1u);   // RNE
  return (u16)(r >> 16);
}
__device__ __forceinline__ float bf2f(u16 s){ return __uint_as_float(((unsigned)s) << 16); }
__device__ __forceinline__ float sigm(float x){ return 1.0f / (1.0f + __expf(-x)); }
__device__ __forceinline__ float tanh_(float x){
  float ax = fabsf(x);
  float e  = __expf(2.0f * ax);
  float r  = 1.0f - 2.0f / (e + 1.0f);
  return copysignf(r, x);
}
__device__ __forceinline__ fx4 mfma(s16x8 a, s16x8 b, fx4 c){
  return __builtin_amdgcn_mfma_f32_16x16x32_bf16(a, b, c, 0, 0, 0);
}

// system-scope relaxed atomics: cache-bypass, no cache-maintenance instructions
__device__ __forceinline__ u64t aload64(const u16* p){
  return __hip_atomic_load((const u64t*)p, __ATOMIC_RELAXED, __HIP_MEMORY_SCOPE_SYSTEM);
}
__device__ __forceinline__ void astore32(u16* p, unsigned v){
  __hip_atomic_store((unsigned*)p, v, __ATOMIC_RELAXED, __HIP_MEMORY_SCOPE_SYSTEM);
}
__device__ __forceinline__ unsigned aload32(const unsigned* p){
  return __hip_atomic_load(p, __ATOMIC_RELAXED, __HIP_MEMORY_SCOPE_SYSTEM);
}
__device__ __forceinline__ unsigned afadd(unsigned* p){
  return __hip_atomic_fetch_add(p, 1u, __ATOMIC_RELAXED, __HIP_MEMORY_SCOPE_SYSTEM);
}

// ---------------- prep kernels ----------------
__global__ void cvt_hilo(const float* __restrict__ src, u16* __restrict__ hi,
                         u16* __restrict__ lo, int n4){
  int i      = blockIdx.x * blockDim.x + threadIdx.x;
  int stride = gridDim.x * blockDim.x;
  for (; i < n4; i += stride){
    fx4 v = ((const fx4*)src)[i];
    u16x4 h, l;
    #pragma unroll
    for (int k = 0; k < 4; ++k){
      u16 hh = f2bf(v[k]);
      h[k] = hh;
      l[k] = f2bf(v[k] - bf2f(hh));
    }
    ((u16x4*)hi)[i] = h;
    ((u16x4*)lo)[i] = l;
  }
}

__global__ void vadd(const float* __restrict__ a, const float* __restrict__ b,
                     float* __restrict__ o, int n){
  int i = blockIdx.x * blockDim.x + threadIdx.x;
  if (i < n) o[i] = a[i] + b[i];
}

__global__ void zero_init(float* cst1, float* cst2,
                          u16* x0, u16* x1, u16* x2, u16* x3, unsigned* bar){
  int i = blockIdx.x * blockDim.x + threadIdx.x;   // 65536 threads
  cst1[i] = 0.0f; cst2[i] = 0.0f;
  ((unsigned*)x0)[i] = 0u;
  ((unsigned*)x1)[i] = 0u;
  ((unsigned*)x2)[i] = 0u;
  ((unsigned*)x3)[i] = 0u;
  if (i < 2048) bar[i] = 0u;
}

// ---------------- bulk GEMM (split-bf16, 128x64 tile) ----------------
template<int KD, int AMODE, int OMODE>
__global__ __launch_bounds__(256)
void gemmX(const float* __restrict__ Af,
           const u16* __restrict__ Ah, const u16* __restrict__ Al,
           const u16* __restrict__ Bh, const u16* __restrict__ Bl,
           const float* __restrict__ bias,
           float* __restrict__ out, int N, int c0)
{
  __shared__ float xt[(OMODE == 0) ? 64 * 130 : 4];
  const int lane = threadIdx.x & 63;
  const int wv   = threadIdx.x >> 6;
  const int l15  = lane & 15;
  const int lhi  = lane >> 4;
  const int koff = lhi * 8;
  const int mb   = blockIdx.x * 128;
  const int nb   = blockIdx.y * 64;
  const int r0   = mb + wv * 32 + l15;

  fx4 acc[2][4] = {};
  for (int kt = 0; kt < KD / 32; ++kt){
    const int kb = kt * 32 + koff;
    s16x8 ah[2], al[2];
    #pragma unroll
    for (int mi = 0; mi < 2; ++mi){
      const int r  = r0 + mi * 16;
      const int b  = r & 63;
      const int tl = r >> 6;
      if (AMODE == 0){
        const float* p = Af + ((size_t)b * T_ + c0 + tl) * KD + kb;
        fx8 v = *reinterpret_cast<const fx8*>(p);
        #pragma unroll
        for (int i = 0; i < 8; ++i){
          u16 h = f2bf(v[i]);
          ah[mi][i] = (short)h;
          al[mi][i] = (short)f2bf(v[i] - bf2f(h));
        }
      } else {
        const size_t ao = ((size_t)b * TC_ + tl) * KD + kb;
        ah[mi] = *reinterpret_cast<const s16x8*>(Ah + ao);
        al[mi] = *reinterpret_cast<const s16x8*>(Al + ao);
      }
    }
    #pragma unroll
    for (int c = 0; c < 4; ++c){
      const size_t wo = (size_t)(nb + c * 16 + l15) * KD + kb;
      s16x8 bh = *reinterpret_cast<const s16x8*>(Bh + wo);
      s16x8 bl = *reinterpret_cast<const s16x8*>(Bl + wo);
      #pragma unroll
      for (int mi = 0; mi < 2; ++mi){
        acc[mi][c] = mfma(ah[mi], bh, acc[mi][c]);
        acc[mi][c] = mfma(ah[mi], bl, acc[mi][c]);
        acc[mi][c] = mfma(al[mi], bh, acc[mi][c]);
      }
    }
  }

  if (OMODE == 0){
    #pragma unroll
    for (int c = 0; c < 4; ++c){
      const int nloc = c * 16 + l15;
      const float bv = bias[nb + nloc];
      #pragma unroll
      for (int mi = 0; mi < 2; ++mi)
        #pragma unroll
        for (int r = 0; r < 4; ++r)
          xt[nloc * 130 + wv * 32 + mi * 16 + lhi * 4 + r] = acc[mi][c][r] + bv;
    }
    __syncthreads();
    const int mloc = threadIdx.x & 127;
    const int b    = mloc & 63;
    const int tl   = blockIdx.x * 2 + (mloc >> 6);
    #pragma unroll
    for (int it = 0; it < 32; ++it){
      const int nloc = (threadIdx.x >> 7) + it * 2;
      const int n = nb + nloc;
      const int g = n >> 10;
      const int j = n & 1023;
      out[((size_t)(tl * 4 + g) * H_ + j) * 64 + b] = xt[nloc * 130 + mloc];
    }
  } else {
    #pragma unroll
    for (int c = 0; c < 4; ++c){
      const int n = nb + c * 16 + l15;
      const float bv = bias[n];
      #pragma unroll
      for (int mi = 0; mi < 2; ++mi)
        #pragma unroll
        for (int r = 0; r < 4; ++r){
          const int m  = mb + wv * 32 + mi * 16 + lhi * 4 + r;
          const int b  = m & 63;
          const int tl = m >> 6;
          out[((size_t)b * T_ + c0 + tl) * (size_t)N + n] = acc[mi][c][r] + bv;
        }
    }
  }
}

// ---------------- two-level grid barrier (relaxed atomics, no fences) ----------
__device__ __forceinline__ void gbar(unsigned* bar, int gid, unsigned ep, int ngrp){
  if (afadd(&bar[gid * 32]) == WPG - 1u){
    __hip_atomic_store(&bar[gid * 32], 0u, __ATOMIC_RELAXED, __HIP_MEMORY_SCOPE_SYSTEM);
    if (afadd(&bar[512]) == (unsigned)(ngrp - 1)){
      __hip_atomic_store(&bar[512], 0u, __ATOMIC_RELAXED, __HIP_MEMORY_SCOPE_SYSTEM);
      astore32((u16*)&bar[544], ep);
    } else {
      while (aload32(&bar[544]) != ep) __builtin_amdgcn_s_sleep(1);
    }
    astore32((u16*)&bar[1024 + gid * 32], ep);
  } else {
    while (aload32(&bar[1024 + gid * 32]) != ep) __builtin_amdgcn_s_sleep(1);
  }
}

// ---------------- persistent dual-layer LSTM chunk ----------------
// Same decomposition as r8 (layer x 4 M-tiles x 32 unit-groups, XCD-pinned by
// blockIdx&7). FIX 1: __launch_bounds__(512,2) -> 256 VGPR budget so the W
// {i,f} half truly stays register-resident for the whole chunk. FIX 2: LDS
// reduce col stride 9 (coprime 32) kills the 8-way write bank conflict.
#define RSTR 577   // row stride floats (16 rows x 64 cols x 9 + pad)
__global__ __launch_bounds__(512, 2)
void lstm_pd(int mode, unsigned ep0, int ngrp,
    const u16* __restrict__ W1h, const u16* __restrict__ W1l,
    const float* __restrict__ xp1, float* __restrict__ cst1,
    u16* __restrict__ hx1h, u16* __restrict__ hx1l,
    u16* __restrict__ ha1h, u16* __restrict__ ha1l,
    const u16* __restrict__ W2h, const u16* __restrict__ W2l,
    const float* __restrict__ xp2, float* __restrict__ cst2,
    u16* __restrict__ hx2h, u16* __restrict__ hx2l,
    u16* __restrict__ ha2h, u16* __restrict__ ha2l,
    unsigned* __restrict__ bar)
{
  __shared__ float red[16 * RSTR];

  const int x8 = blockIdx.x & 7;
  const int q  = blockIdx.x >> 3;
  int part, m4, ghi;
  if (mode == 3){ part = q & 1;    m4 = (q >> 1) & 3; ghi = q >> 3; }
  else          { part = mode - 1; m4 = q & 3;        ghi = q >> 2; }
  const int jb  = (x8 + 8 * ghi) * 32;    // unit base (0..992)
  const int mb  = m4 * 16;                // batch-row base
  const int gid = blockIdx.x >> 4;

  const u16*   Wh  = part ? W2h  : W1h;
  const u16*   Wl  = part ? W2l  : W1l;
  const float* xp  = part ? xp2  : xp1;
  float*       cst = part ? cst2 : cst1;
  u16*         hxh = part ? hx2h : hx1h;
  u16*         hxl = part ? hx2l : hx1l;
  u16*         hah = part ? ha2h : ha1h;
  u16*         hal = part ? ha2l : ha1l;

  const int tid  = threadIdx.x;
  const int lane = tid & 63;
  const int wv   = tid >> 6;              // 0..7 = K slice
  const int l15  = lane & 15;
  const int lhi  = lane >> 4;
  const int kb0  = wv * 128 + lhi * 8;

  size_t wrowR[4], wrowS[4];
  #pragma unroll
  for (int ct = 0; ct < 4; ++ct){
    const int clR = ct * 16 + l15;
    const int clS = (ct + 4) * 16 + l15;
    wrowR[ct] = (size_t)((clR >> 5) * H_ + jb + (clR & 31));
    wrowS[ct] = (size_t)((clS >> 5) * H_ + jb + (clS & 31));
  }

  // register-resident W for gates i,f (coltiles 0-3), whole chunk (128 VGPRs)
  s16x8 wrh[4][4], wrl[4][4];
  #pragma unroll
  for (int ct = 0; ct < 4; ++ct)
    #pragma unroll
    for (int s = 0; s < 4; ++s){
      const size_t wo = wrowR[ct] * H_ + kb0 + s * 32;
      wrh[ct][s] = *reinterpret_cast<const s16x8*>(Wh + wo);
      wrl[ct][s] = *reinterpret_cast<const s16x8*>(Wl + wo);
    }

  // epilogue identity: tid<256 -> (batch row, unit pair)
  const int up = tid & 15;
  const int mm = tid >> 4;                // 0..15 when tid<256
  const int u0 = 2 * up;
  const int j0 = jb + u0;
  const int eb = mb + mm;
  float cva = 0.0f, cvb = 0.0f;
  if (tid < 256){
    cva = cst[(size_t)j0 * B_ + eb];
    cvb = cst[(size_t)(j0 + 1) * B_ + eb];
  }

  for (int tl = 0; tl < TC_; ++tl){
    const int par = tl & 1;
    const u16* rph = hxh + par * (64 * H_);
    const u16* rpl = hxl + par * (64 * H_);
    u16* nph = hxh + (par ^ 1) * (64 * H_);
    u16* npl = hxl + (par ^ 1) * (64 * H_);

    float xq0[4], xq1[4];
    if (tid < 256){
      #pragma unroll
      for (int g = 0; g < 4; ++g){
        const float* xr = xp + ((size_t)(tl * 4 + g) * H_ + j0) * 64 + eb;
        xq0[g] = xr[0];
        xq1[g] = xr[64];
      }
    }

    // ---- GEMM: h[16 rows] x W[128 cols], K-slice per wave ----
    fx4 acc[8] = {};
    #pragma unroll
    for (int s = 0; s < 4; ++s){
      const int kb = kb0 + s * 32;
      const u16* ph = rph + (size_t)(mb + l15) * H_ + kb;
      const u16* pl = rpl + (size_t)(mb + l15) * H_ + kb;
      union { u64t u[2]; s16x8 v; } ua, ul;
      ua.u[0] = aload64(ph);  ua.u[1] = aload64(ph + 4);
      ul.u[0] = aload64(pl);  ul.u[1] = aload64(pl + 4);
      #pragma unroll
      for (int ct = 0; ct < 4; ++ct){
        acc[ct] = mfma(ua.v, wrh[ct][s], acc[ct]);
        acc[ct] = mfma(ua.v, wrl[ct][s], acc[ct]);
        acc[ct] = mfma(ul.v, wrh[ct][s], acc[ct]);
      }
      #pragma unroll
      for (int ct = 0; ct < 4; ++ct){
        const size_t wo = wrowS[ct] * H_ + kb;
        s16x8 bh = *reinterpret_cast<const s16x8*>(Wh + wo);
        s16x8 bl = *reinterpret_cast<const s16x8*>(Wl + wo);
        acc[4 + ct] = mfma(ua.v, bh, acc[4 + ct]);
        acc[4 + ct] = mfma(ua.v, bl, acc[4 + ct]);
        acc[4 + ct] = mfma(ul.v, bh, acc[4 + ct]);
      }
    }

    // ---- phase A reduce: coltiles 0-3 (gates i,f); col stride 9 ----
    #pragma unroll
    for (int ct = 0; ct < 4; ++ct)
      #pragma unroll
      for (int r = 0; r < 4; ++r)
        red[(lhi * 4 + r) * RSTR + (ct * 16 + l15) * 9 + wv] = acc[ct][r];
    __syncthreads();
    float i0s = 0, i1s = 0, f0s = 0, f1s = 0;
    if (tid < 256){
      const float* r0 = red + mm * RSTR + (u0) * 9;
      const float* r1 = red + mm * RSTR + (u0 + 1) * 9;
      const float* r2 = red + mm * RSTR + (32 + u0) * 9;
      const float* r3 = red + mm * RSTR + (32 + u0 + 1) * 9;
      #pragma unroll
      for (int w = 0; w < 8; ++w){
        i0s += r0[w]; i1s += r1[w]; f0s += r2[w]; f1s += r3[w];
      }
    }
    __syncthreads();

    // ---- phase B reduce: coltiles 4-7 (gates g,o) ----
    #pragma unroll
    for (int ct = 0; ct < 4; ++ct)
      #pragma unroll
      for (int r = 0; r < 4; ++r)
        red[(lhi * 4 + r) * RSTR + (ct * 16 + l15) * 9 + wv] = acc[4 + ct][r];
    __syncthreads();

    if (tid < 256){
      float g0s = 0, g1s = 0, o0s = 0, o1s = 0;
      const float* r0 = red + mm * RSTR + (u0) * 9;
      const float* r1 = red + mm * RSTR + (u0 + 1) * 9;
      const float* r2 = red + mm * RSTR + (32 + u0) * 9;
      const float* r3 = red + mm * RSTR + (32 + u0 + 1) * 9;
      #pragma unroll
      for (int w = 0; w < 8; ++w){
        g0s += r0[w]; g1s += r1[w]; o0s += r2[w]; o1s += r3[w];
      }
      float iv = sigm (i0s + xq0[0]);
      float fv = sigm (f0s + xq0[1]);
      float gv = tanh_(g0s + xq0[2]);
      float ov = sigm (o0s + xq0[3]);
      float cn = fv * cva + iv * gv;
      float h0 = ov * tanh_(cn);
      cva = cn;
      iv = sigm (i1s + xq1[0]);
      fv = sigm (f1s + xq1[1]);
      gv = tanh_(g1s + xq1[2]);
      ov = sigm (o1s + xq1[3]);
      cn = fv * cvb + iv * gv;
      float h1 = ov * tanh_(cn);
      cvb = cn;

      u16 h0h = f2bf(h0), h0l = f2bf(h0 - bf2f(h0h));
      u16 h1h = f2bf(h1), h1l = f2bf(h1 - bf2f(h1h));
      astore32(nph + (size_t)eb * H_ + j0, (unsigned)h0h | ((unsigned)h1h << 16));
      astore32(npl + (size_t)eb * H_ + j0, (unsigned)h0l | ((unsigned)h1l << 16));
      const size_t ai = ((size_t)eb * TC_ + tl) * H_ + j0;
      *(unsigned*)(hah + ai) = (unsigned)h0h | ((unsigned)h1h << 16);
      *(unsigned*)(hal + ai) = (unsigned)h0l | ((unsigned)h1l << 16);
    }

    __syncthreads();                      // drains vmcnt before signal
    if (tid == 0) gbar(bar, gid, ep0 + tl + 1, ngrp);
    __syncthreads();
  }
  if (tid < 256){
    cst[(size_t)j0 * B_ + eb]       = cva;
    cst[(size_t)(j0 + 1) * B_ + eb] = cvb;
  }
}

// ---------------- host launch ----------------
extern "C" void kernel_launch(void* const* d_in, const int* in_sizes, int n_in,
                              void* d_out, int out_size, void* d_ws, size_t ws_size,
                              hipStream_t stream)
{
  const float* x    = (const float*)d_in[0];
  const float* Wih1 = (const float*)d_in[1];
  const float* Whh1 = (const float*)d_in[2];
  const float* bih1 = (const float*)d_in[3];
  const float* bhh1 = (const float*)d_in[4];
  const float* Wih2 = (const float*)d_in[5];
  const float* Whh2 = (const float*)d_in[6];
  const float* bih2 = (const float*)d_in[7];
  const float* bhh2 = (const float*)d_in[8];
  const float* fcW  = (const float*)d_in[9];
  const float* fcb  = (const float*)d_in[10];
  float* out = (float*)d_out;
  (void)in_sizes; (void)n_in; (void)out_size; (void)ws_size;

  char* base = (char*)d_ws;
  size_t off = 0;
  auto alloc = [&](size_t bytes) -> void* {
    void* p = base + off;
    off = (off + bytes + 255) & ~(size_t)255;
    return p;
  };
  u16* Wih1_hi = (u16*)alloc((size_t)G4_ * I_ * 2);
  u16* Wih1_lo = (u16*)alloc((size_t)G4_ * I_ * 2);
  u16* Whh1_hi = (u16*)alloc((size_t)G4_ * H_ * 2);
  u16* Whh1_lo = (u16*)alloc((size_t)G4_ * H_ * 2);
  u16* Wih2_hi = (u16*)alloc((size_t)G4_ * H_ * 2);
  u16* Wih2_lo = (u16*)alloc((size_t)G4_ * H_ * 2);
  u16* Whh2_hi = (u16*)alloc((size_t)G4_ * H_ * 2);
  u16* Whh2_lo = (u16*)alloc((size_t)G4_ * H_ * 2);
  u16* fcW_hi  = (u16*)alloc((size_t)O_ * H_ * 2);
  u16* fcW_lo  = (u16*)alloc((size_t)O_ * H_ * 2);
  float* bsum1 = (float*)alloc((size_t)G4_ * 4);
  float* bsum2 = (float*)alloc((size_t)G4_ * 4);
  float* cst1  = (float*)alloc((size_t)B_ * H_ * 4);
  float* cst2  = (float*)alloc((size_t)B_ * H_ * 4);
  u16* hx1h = (u16*)alloc((size_t)2 * B_ * H_ * 2);
  u16* hx1l = (u16*)alloc((size_t)2 * B_ * H_ * 2);
  u16* hx2h = (u16*)alloc((size_t)2 * B_ * H_ * 2);
  u16* hx2l = (u16*)alloc((size_t)2 * B_ * H_ * 2);
  u16* h1s_hi = (u16*)alloc((size_t)B_ * TC_ * H_ * 2);
  u16* h1s_lo = (u16*)alloc((size_t)B_ * TC_ * H_ * 2);
  u16* h2s_hi = (u16*)alloc((size_t)B_ * TC_ * H_ * 2);
  u16* h2s_lo = (u16*)alloc((size_t)B_ * TC_ * H_ * 2);
  float* xp1  = (float*)alloc((size_t)TC_ * G4_ * B_ * 4);
  float* xp2  = (float*)alloc((size_t)TC_ * G4_ * B_ * 4);
  unsigned* bar = (unsigned*)alloc(2048 * 4);

  // ---- prep ----
  cvt_hilo<<<512, 256, 0, stream>>>(Wih1, Wih1_hi, Wih1_lo, G4_ * I_ / 4);
  cvt_hilo<<<512, 256, 0, stream>>>(Whh1, Whh1_hi, Whh1_lo, G4_ * H_ / 4);
  cvt_hilo<<<512, 256, 0, stream>>>(Wih2, Wih2_hi, Wih2_lo, G4_ * H_ / 4);
  cvt_hilo<<<512, 256, 0, stream>>>(Whh2, Whh2_hi, Whh2_lo, G4_ * H_ / 4);
  cvt_hilo<<<256, 256, 0, stream>>>(fcW,  fcW_hi,  fcW_lo,  O_ * H_ / 4);
  vadd<<<16, 256, 0, stream>>>(bih1, bhh1, bsum1, G4_);
  vadd<<<16, 256, 0, stream>>>(bih2, bhh2, bsum2, G4_);
  zero_init<<<256, 256, 0, stream>>>(cst1, cst2, hx1h, hx1l, hx2h, hx2l, bar);

  const dim3 gX(32, 64);
  const dim3 gF(32, 8);

  gemmX<I_, 0, 0><<<gX, 256, 0, stream>>>(
      x, nullptr, nullptr, Wih1_hi, Wih1_lo, bsum1, xp1, G4_, 0);

  unsigned ep = 0;
  for (int c = 0; c <= NCH; ++c){
    const int mode = ((c < NCH) ? 1 : 0) | ((c >= 1) ? 2 : 0);
    const int nwg  = (mode == 3) ? 256 : 128;
    int ngrp = nwg / WPG;
    {
      void* args[] = { (void*)&mode, (void*)&ep, (void*)&ngrp,
                       (void*)&Whh1_hi, (void*)&Whh1_lo, (void*)&xp1, (void*)&cst1,
                       (void*)&hx1h, (void*)&hx1l, (void*)&h1s_hi, (void*)&h1s_lo,
                       (void*)&Whh2_hi, (void*)&Whh2_lo, (void*)&xp2, (void*)&cst2,
                       (void*)&hx2h, (void*)&hx2l, (void*)&h2s_hi, (void*)&h2s_lo,
                       (void*)&bar };
      hipLaunchCooperativeKernel((const void*)lstm_pd, dim3(nwg), dim3(512),
                                 args, 0, stream);
      ep += TC_;
    }
    if (c < NCH)
      gemmX<H_, 1, 0><<<gX, 256, 0, stream>>>(
          nullptr, h1s_hi, h1s_lo, Wih2_hi, Wih2_lo, bsum2, xp2, G4_, 0);
    if (c + 1 < NCH)
      gemmX<I_, 0, 0><<<gX, 256, 0, stream>>>(
          x, nullptr, nullptr, Wih1_hi, Wih1_lo, bsum1, xp1, G4_, (c + 1) * TC_);
    if (c >= 1)
      gemmX<H_, 1, 1><<<gF, 256, 0, stream>>>(
          nullptr, h2s_hi, h2s_lo, fcW_hi, fcW_lo, fcb, out, O_, (c - 1) * TC_);
  }
}

// Round 10
// 13008.977 us; speedup vs baseline: 1.2668x; 1.0210x over previous
//
#include <hip/hip_runtime.h>
#include <hip/hip_bf16.h>
#include <math.h>

#define B_  64
#define T_  512
#define I_  512
#define H_  1024
#define G4_ 4096
#define O_  512
#define TC_ 64             // time chunk
#define NCH (T_ / TC_)     // 8
#define WPG 16             // WGs per barrier group

typedef short  s16x8 __attribute__((ext_vector_type(8)));
typedef float  fx4   __attribute__((ext_vector_type(4)));
typedef float  fx8   __attribute__((ext_vector_type(8)));
typedef unsigned short u16;
typedef u16    u16x4 __attribute__((ext_vector_type(4)));
typedef unsigned long long u64t;

__device__ __forceinline__ u16 f2bf(float f){
  unsigned u = __float_as_uint(f);
  unsigned r = u + 0x7fffu + ((u >> 16) & 1u);   // RNE
  return (u16)(r >> 16);
}
__device__ __forceinline__ float bf2f(u16 s){ return __uint_as_float(((unsigned)s) << 16); }
__device__ __forceinline__ float sigm(float x){ return 1.0f / (1.0f + __expf(-x)); }
__device__ __forceinline__ float tanh_(float x){
  float ax = fabsf(x);
  float e  = __expf(2.0f * ax);
  float r  = 1.0f - 2.0f / (e + 1.0f);
  return copysignf(r, x);
}
__device__ __forceinline__ fx4 mfma(s16x8 a, s16x8 b, fx4 c){
  return __builtin_amdgcn_mfma_f32_16x16x32_bf16(a, b, c, 0, 0, 0);
}
// Opaque register clamp: after this, reload-from-memory is ILLEGAL (asm output
// is the only valid copy) -> the value must stay register-resident.
__device__ __forceinline__ void keepreg(s16x8& v){ asm volatile("" : "+v"(v)); }

// system-scope relaxed atomics: cache-bypass, no cache-maintenance instructions
__device__ __forceinline__ u64t aload64(const u16* p){
  return __hip_atomic_load((const u64t*)p, __ATOMIC_RELAXED, __HIP_MEMORY_SCOPE_SYSTEM);
}
__device__ __forceinline__ void astore32(u16* p, unsigned v){
  __hip_atomic_store((unsigned*)p, v, __ATOMIC_RELAXED, __HIP_MEMORY_SCOPE_SYSTEM);
}
__device__ __forceinline__ unsigned aload32(const unsigned* p){
  return __hip_atomic_load(p, __ATOMIC_RELAXED, __HIP_MEMORY_SCOPE_SYSTEM);
}
__device__ __forceinline__ unsigned afadd(unsigned* p){
  return __hip_atomic_fetch_add(p, 1u, __ATOMIC_RELAXED, __HIP_MEMORY_SCOPE_SYSTEM);
}

// ---------------- prep kernels ----------------
__global__ void cvt_hilo(const float* __restrict__ src, u16* __restrict__ hi,
                         u16* __restrict__ lo, int n4){
  int i      = blockIdx.x * blockDim.x + threadIdx.x;
  int stride = gridDim.x * blockDim.x;
  for (; i < n4; i += stride){
    fx4 v = ((const fx4*)src)[i];
    u16x4 h, l;
    #pragma unroll
    for (int k = 0; k < 4; ++k){
      u16 hh = f2bf(v[k]);
      h[k] = hh;
      l[k] = f2bf(v[k] - bf2f(hh));
    }
    ((u16x4*)hi)[i] = h;
    ((u16x4*)lo)[i] = l;
  }
}

__global__ void vadd(const float* __restrict__ a, const float* __restrict__ b,
                     float* __restrict__ o, int n){
  int i = blockIdx.x * blockDim.x + threadIdx.x;
  if (i < n) o[i] = a[i] + b[i];
}

__global__ void zero_init(float* cst1, float* cst2,
                          u16* x0, u16* x1, u16* x2, u16* x3, unsigned* bar){
  int i = blockIdx.x * blockDim.x + threadIdx.x;   // 65536 threads
  cst1[i] = 0.0f; cst2[i] = 0.0f;
  ((unsigned*)x0)[i] = 0u;
  ((unsigned*)x1)[i] = 0u;
  ((unsigned*)x2)[i] = 0u;
  ((unsigned*)x3)[i] = 0u;
  if (i < 2048) bar[i] = 0u;
}

// ---------------- bulk GEMM (split-bf16, 128x64 tile) ----------------
template<int KD, int AMODE, int OMODE>
__global__ __launch_bounds__(256)
void gemmX(const float* __restrict__ Af,
           const u16* __restrict__ Ah, const u16* __restrict__ Al,
           const u16* __restrict__ Bh, const u16* __restrict__ Bl,
           const float* __restrict__ bias,
           float* __restrict__ out, int N, int c0)
{
  __shared__ float xt[(OMODE == 0) ? 64 * 130 : 4];
  const int lane = threadIdx.x & 63;
  const int wv   = threadIdx.x >> 6;
  const int l15  = lane & 15;
  const int lhi  = lane >> 4;
  const int koff = lhi * 8;
  const int mb   = blockIdx.x * 128;
  const int nb   = blockIdx.y * 64;
  const int r0   = mb + wv * 32 + l15;

  fx4 acc[2][4] = {};
  for (int kt = 0; kt < KD / 32; ++kt){
    const int kb = kt * 32 + koff;
    s16x8 ah[2], al[2];
    #pragma unroll
    for (int mi = 0; mi < 2; ++mi){
      const int r  = r0 + mi * 16;
      const int b  = r & 63;
      const int tl = r >> 6;
      if (AMODE == 0){
        const float* p = Af + ((size_t)b * T_ + c0 + tl) * KD + kb;
        fx8 v = *reinterpret_cast<const fx8*>(p);
        #pragma unroll
        for (int i = 0; i < 8; ++i){
          u16 h = f2bf(v[i]);
          ah[mi][i] = (short)h;
          al[mi][i] = (short)f2bf(v[i] - bf2f(h));
        }
      } else {
        const size_t ao = ((size_t)b * TC_ + tl) * KD + kb;
        ah[mi] = *reinterpret_cast<const s16x8*>(Ah + ao);
        al[mi] = *reinterpret_cast<const s16x8*>(Al + ao);
      }
    }
    #pragma unroll
    for (int c = 0; c < 4; ++c){
      const size_t wo = (size_t)(nb + c * 16 + l15) * KD + kb;
      s16x8 bh = *reinterpret_cast<const s16x8*>(Bh + wo);
      s16x8 bl = *reinterpret_cast<const s16x8*>(Bl + wo);
      #pragma unroll
      for (int mi = 0; mi < 2; ++mi){
        acc[mi][c] = mfma(ah[mi], bh, acc[mi][c]);
        acc[mi][c] = mfma(ah[mi], bl, acc[mi][c]);
        acc[mi][c] = mfma(al[mi], bh, acc[mi][c]);
      }
    }
  }

  if (OMODE == 0){
    #pragma unroll
    for (int c = 0; c < 4; ++c){
      const int nloc = c * 16 + l15;
      const float bv = bias[nb + nloc];
      #pragma unroll
      for (int mi = 0; mi < 2; ++mi)
        #pragma unroll
        for (int r = 0; r < 4; ++r)
          xt[nloc * 130 + wv * 32 + mi * 16 + lhi * 4 + r] = acc[mi][c][r] + bv;
    }
    __syncthreads();
    const int mloc = threadIdx.x & 127;
    const int b    = mloc & 63;
    const int tl   = blockIdx.x * 2 + (mloc >> 6);
    #pragma unroll
    for (int it = 0; it < 32; ++it){
      const int nloc = (threadIdx.x >> 7) + it * 2;
      const int n = nb + nloc;
      const int g = n >> 10;
      const int j = n & 1023;
      out[((size_t)(tl * 4 + g) * H_ + j) * 64 + b] = xt[nloc * 130 + mloc];
    }
  } else {
    #pragma unroll
    for (int c = 0; c < 4; ++c){
      const int n = nb + c * 16 + l15;
      const float bv = bias[n];
      #pragma unroll
      for (int mi = 0; mi < 2; ++mi)
        #pragma unroll
        for (int r = 0; r < 4; ++r){
          const int m  = mb + wv * 32 + mi * 16 + lhi * 4 + r;
          const int b  = m & 63;
          const int tl = m >> 6;
          out[((size_t)b * T_ + c0 + tl) * (size_t)N + n] = acc[mi][c][r] + bv;
        }
    }
  }
}

// ---------------- two-level grid barrier (relaxed atomics, no fences) ----------
__device__ __forceinline__ void gbar(unsigned* bar, int gid, unsigned ep, int ngrp){
  if (afadd(&bar[gid * 32]) == WPG - 1u){
    __hip_atomic_store(&bar[gid * 32], 0u, __ATOMIC_RELAXED, __HIP_MEMORY_SCOPE_SYSTEM);
    if (afadd(&bar[512]) == (unsigned)(ngrp - 1)){
      __hip_atomic_store(&bar[512], 0u, __ATOMIC_RELAXED, __HIP_MEMORY_SCOPE_SYSTEM);
      astore32((u16*)&bar[544], ep);
    } else {
      while (aload32(&bar[544]) != ep) __builtin_amdgcn_s_sleep(1);
    }
    astore32((u16*)&bar[1024 + gid * 32], ep);
  } else {
    while (aload32(&bar[1024 + gid * 32]) != ep) __builtin_amdgcn_s_sleep(1);
  }
}

// ---------------- persistent dual-layer LSTM chunk ----------------
// r9 + two changes: (1) amdgpu_waves_per_eu(2,2) pins allocator at 2 waves/EU
// (256-VGPR budget; 512-thr WG = 8 waves = exactly 2/EU, grid = 1 WG/CU);
// (2) keepreg() opaque-clamps the preloaded W {i,f} fragments so the compiler
// cannot legally re-load them inside the step loop (r8/r9: W re-streamed from
// HBM every step, FETCH 1.5 GB/chunk).
#define RSTR 577   // LDS row stride floats (col stride 9, coprime with 32 banks)
__global__ __launch_bounds__(512) __attribute__((amdgpu_waves_per_eu(2, 2)))
void lstm_pd(int mode, unsigned ep0, int ngrp,
    const u16* __restrict__ W1h, const u16* __restrict__ W1l,
    const float* __restrict__ xp1, float* __restrict__ cst1,
    u16* __restrict__ hx1h, u16* __restrict__ hx1l,
    u16* __restrict__ ha1h, u16* __restrict__ ha1l,
    const u16* __restrict__ W2h, const u16* __restrict__ W2l,
    const float* __restrict__ xp2, float* __restrict__ cst2,
    u16* __restrict__ hx2h, u16* __restrict__ hx2l,
    u16* __restrict__ ha2h, u16* __restrict__ ha2l,
    unsigned* __restrict__ bar)
{
  __shared__ float red[16 * RSTR];

  const int x8 = blockIdx.x & 7;
  const int q  = blockIdx.x >> 3;
  int part, m4, ghi;
  if (mode == 3){ part = q & 1;    m4 = (q >> 1) & 3; ghi = q >> 3; }
  else          { part = mode - 1; m4 = q & 3;        ghi = q >> 2; }
  const int jb  = (x8 + 8 * ghi) * 32;    // unit base (0..992)
  const int mb  = m4 * 16;                // batch-row base
  const int gid = blockIdx.x >> 4;

  const u16*   Wh  = part ? W2h  : W1h;
  const u16*   Wl  = part ? W2l  : W1l;
  const float* xp  = part ? xp2  : xp1;
  float*       cst = part ? cst2 : cst1;
  u16*         hxh = part ? hx2h : hx1h;
  u16*         hxl = part ? hx2l : hx1l;
  u16*         hah = part ? ha2h : ha1h;
  u16*         hal = part ? ha2l : ha1l;

  const int tid  = threadIdx.x;
  const int lane = tid & 63;
  const int wv   = tid >> 6;              // 0..7 = K slice
  const int l15  = lane & 15;
  const int lhi  = lane >> 4;
  const int kb0  = wv * 128 + lhi * 8;

  size_t wrowR[4], wrowS[4];
  #pragma unroll
  for (int ct = 0; ct < 4; ++ct){
    const int clR = ct * 16 + l15;
    const int clS = (ct + 4) * 16 + l15;
    wrowR[ct] = (size_t)((clR >> 5) * H_ + jb + (clR & 31));
    wrowS[ct] = (size_t)((clS >> 5) * H_ + jb + (clS & 31));
  }

  // register-resident W for gates i,f (coltiles 0-3), whole chunk (128 VGPRs)
  s16x8 wrh[4][4], wrl[4][4];
  #pragma unroll
  for (int ct = 0; ct < 4; ++ct)
    #pragma unroll
    for (int s = 0; s < 4; ++s){
      const size_t wo = wrowR[ct] * H_ + kb0 + s * 32;
      wrh[ct][s] = *reinterpret_cast<const s16x8*>(Wh + wo);
      wrl[ct][s] = *reinterpret_cast<const s16x8*>(Wl + wo);
      keepreg(wrh[ct][s]);
      keepreg(wrl[ct][s]);
    }

  // epilogue identity: tid<256 -> (batch row, unit pair)
  const int up = tid & 15;
  const int mm = tid >> 4;                // 0..15 when tid<256
  const int u0 = 2 * up;
  const int j0 = jb + u0;
  const int eb = mb + mm;
  float cva = 0.0f, cvb = 0.0f;
  if (tid < 256){
    cva = cst[(size_t)j0 * B_ + eb];
    cvb = cst[(size_t)(j0 + 1) * B_ + eb];
  }

  for (int tl = 0; tl < TC_; ++tl){
    const int par = tl & 1;
    const u16* rph = hxh + par * (64 * H_);
    const u16* rpl = hxl + par * (64 * H_);
    u16* nph = hxh + (par ^ 1) * (64 * H_);
    u16* npl = hxl + (par ^ 1) * (64 * H_);

    float xq0[4], xq1[4];
    if (tid < 256){
      #pragma unroll
      for (int g = 0; g < 4; ++g){
        const float* xr = xp + ((size_t)(tl * 4 + g) * H_ + j0) * 64 + eb;
        xq0[g] = xr[0];
        xq1[g] = xr[64];
      }
    }

    // ---- GEMM: h[16 rows] x W[128 cols], K-slice per wave ----
    fx4 acc[8] = {};
    #pragma unroll
    for (int s = 0; s < 4; ++s){
      const int kb = kb0 + s * 32;
      const u16* ph = rph + (size_t)(mb + l15) * H_ + kb;
      const u16* pl = rpl + (size_t)(mb + l15) * H_ + kb;
      union { u64t u[2]; s16x8 v; } ua, ul;
      ua.u[0] = aload64(ph);  ua.u[1] = aload64(ph + 4);
      ul.u[0] = aload64(pl);  ul.u[1] = aload64(pl + 4);
      #pragma unroll
      for (int ct = 0; ct < 4; ++ct){
        acc[ct] = mfma(ua.v, wrh[ct][s], acc[ct]);
        acc[ct] = mfma(ua.v, wrl[ct][s], acc[ct]);
        acc[ct] = mfma(ul.v, wrh[ct][s], acc[ct]);
      }
      #pragma unroll
      for (int ct = 0; ct < 4; ++ct){
        const size_t wo = wrowS[ct] * H_ + kb;
        s16x8 bh = *reinterpret_cast<const s16x8*>(Wh + wo);
        s16x8 bl = *reinterpret_cast<const s16x8*>(Wl + wo);
        acc[4 + ct] = mfma(ua.v, bh, acc[4 + ct]);
        acc[4 + ct] = mfma(ua.v, bl, acc[4 + ct]);
        acc[4 + ct] = mfma(ul.v, bh, acc[4 + ct]);
      }
    }

    // ---- phase A reduce: coltiles 0-3 (gates i,f); col stride 9 ----
    #pragma unroll
    for (int ct = 0; ct < 4; ++ct)
      #pragma unroll
      for (int r = 0; r < 4; ++r)
        red[(lhi * 4 + r) * RSTR + (ct * 16 + l15) * 9 + wv] = acc[ct][r];
    __syncthreads();
    float i0s = 0, i1s = 0, f0s = 0, f1s = 0;
    if (tid < 256){
      const float* r0 = red + mm * RSTR + (u0) * 9;
      const float* r1 = red + mm * RSTR + (u0 + 1) * 9;
      const float* r2 = red + mm * RSTR + (32 + u0) * 9;
      const float* r3 = red + mm * RSTR + (32 + u0 + 1) * 9;
      #pragma unroll
      for (int w = 0; w < 8; ++w){
        i0s += r0[w]; i1s += r1[w]; f0s += r2[w]; f1s += r3[w];
      }
    }
    __syncthreads();

    // ---- phase B reduce: coltiles 4-7 (gates g,o) ----
    #pragma unroll
    for (int ct = 0; ct < 4; ++ct)
      #pragma unroll
      for (int r = 0; r < 4; ++r)
        red[(lhi * 4 + r) * RSTR + (ct * 16 + l15) * 9 + wv] = acc[4 + ct][r];
    __syncthreads();

    if (tid < 256){
      float g0s = 0, g1s = 0, o0s = 0, o1s = 0;
      const float* r0 = red + mm * RSTR + (u0) * 9;
      const float* r1 = red + mm * RSTR + (u0 + 1) * 9;
      const float* r2 = red + mm * RSTR + (32 + u0) * 9;
      const float* r3 = red + mm * RSTR + (32 + u0 + 1) * 9;
      #pragma unroll
      for (int w = 0; w < 8; ++w){
        g0s += r0[w]; g1s += r1[w]; o0s += r2[w]; o1s += r3[w];
      }
      float iv = sigm (i0s + xq0[0]);
      float fv = sigm (f0s + xq0[1]);
      float gv = tanh_(g0s + xq0[2]);
      float ov = sigm (o0s + xq0[3]);
      float cn = fv * cva + iv * gv;
      float h0 = ov * tanh_(cn);
      cva = cn;
      iv = sigm (i1s + xq1[0]);
      fv = sigm (f1s + xq1[1]);
      gv = tanh_(g1s + xq1[2]);
      ov = sigm (o1s + xq1[3]);
      cn = fv * cvb + iv * gv;
      float h1 = ov * tanh_(cn);
      cvb = cn;

      u16 h0h = f2bf(h0), h0l = f2bf(h0 - bf2f(h0h));
      u16 h1h = f2bf(h1), h1l = f2bf(h1 - bf2f(h1h));
      astore32(nph + (size_t)eb * H_ + j0, (unsigned)h0h | ((unsigned)h1h << 16));
      astore32(npl + (size_t)eb * H_ + j0, (unsigned)h0l | ((unsigned)h1l << 16));
      const size_t ai = ((size_t)eb * TC_ + tl) * H_ + j0;
      *(unsigned*)(hah + ai) = (unsigned)h0h | ((unsigned)h1h << 16);
      *(unsigned*)(hal + ai) = (unsigned)h0l | ((unsigned)h1l << 16);
    }

    __syncthreads();                      // drains vmcnt before signal
    if (tid == 0) gbar(bar, gid, ep0 + tl + 1, ngrp);
    __syncthreads();
  }
  if (tid < 256){
    cst[(size_t)j0 * B_ + eb]       = cva;
    cst[(size_t)(j0 + 1) * B_ + eb] = cvb;
  }
}

// ---------------- host launch ----------------
extern "C" void kernel_launch(void* const* d_in, const int* in_sizes, int n_in,
                              void* d_out, int out_size, void* d_ws, size_t ws_size,
                              hipStream_t stream)
{
  const float* x    = (const float*)d_in[0];
  const float* Wih1 = (const float*)d_in[1];
  const float* Whh1 = (const float*)d_in[2];
  const float* bih1 = (const float*)d_in[3];
  const float* bhh1 = (const float*)d_in[4];
  const float* Wih2 = (const float*)d_in[5];
  const float* Whh2 = (const float*)d_in[6];
  const float* bih2 = (const float*)d_in[7];
  const float* bhh2 = (const float*)d_in[8];
  const float* fcW  = (const float*)d_in[9];
  const float* fcb  = (const float*)d_in[10];
  float* out = (float*)d_out;
  (void)in_sizes; (void)n_in; (void)out_size; (void)ws_size;

  char* base = (char*)d_ws;
  size_t off = 0;
  auto alloc = [&](size_t bytes) -> void* {
    void* p = base + off;
    off = (off + bytes + 255) & ~(size_t)255;
    return p;
  };
  u16* Wih1_hi = (u16*)alloc((size_t)G4_ * I_ * 2);
  u16* Wih1_lo = (u16*)alloc((size_t)G4_ * I_ * 2);
  u16* Whh1_hi = (u16*)alloc((size_t)G4_ * H_ * 2);
  u16* Whh1_lo = (u16*)alloc((size_t)G4_ * H_ * 2);
  u16* Wih2_hi = (u16*)alloc((size_t)G4_ * H_ * 2);
  u16* Wih2_lo = (u16*)alloc((size_t)G4_ * H_ * 2);
  u16* Whh2_hi = (u16*)alloc((size_t)G4_ * H_ * 2);
  u16* Whh2_lo = (u16*)alloc((size_t)G4_ * H_ * 2);
  u16* fcW_hi  = (u16*)alloc((size_t)O_ * H_ * 2);
  u16* fcW_lo  = (u16*)alloc((size_t)O_ * H_ * 2);
  float* bsum1 = (float*)alloc((size_t)G4_ * 4);
  float* bsum2 = (float*)alloc((size_t)G4_ * 4);
  float* cst1  = (float*)alloc((size_t)B_ * H_ * 4);
  float* cst2  = (float*)alloc((size_t)B_ * H_ * 4);
  u16* hx1h = (u16*)alloc((size_t)2 * B_ * H_ * 2);
  u16* hx1l = (u16*)alloc((size_t)2 * B_ * H_ * 2);
  u16* hx2h = (u16*)alloc((size_t)2 * B_ * H_ * 2);
  u16* hx2l = (u16*)alloc((size_t)2 * B_ * H_ * 2);
  u16* h1s_hi = (u16*)alloc((size_t)B_ * TC_ * H_ * 2);
  u16* h1s_lo = (u16*)alloc((size_t)B_ * TC_ * H_ * 2);
  u16* h2s_hi = (u16*)alloc((size_t)B_ * TC_ * H_ * 2);
  u16* h2s_lo = (u16*)alloc((size_t)B_ * TC_ * H_ * 2);
  float* xp1  = (float*)alloc((size_t)TC_ * G4_ * B_ * 4);
  float* xp2  = (float*)alloc((size_t)TC_ * G4_ * B_ * 4);
  unsigned* bar = (unsigned*)alloc(2048 * 4);

  // ---- prep ----
  cvt_hilo<<<512, 256, 0, stream>>>(Wih1, Wih1_hi, Wih1_lo, G4_ * I_ / 4);
  cvt_hilo<<<512, 256, 0, stream>>>(Whh1, Whh1_hi, Whh1_lo, G4_ * H_ / 4);
  cvt_hilo<<<512, 256, 0, stream>>>(Wih2, Wih2_hi, Wih2_lo, G4_ * H_ / 4);
  cvt_hilo<<<512, 256, 0, stream>>>(Whh2, Whh2_hi, Whh2_lo, G4_ * H_ / 4);
  cvt_hilo<<<256, 256, 0, stream>>>(fcW,  fcW_hi,  fcW_lo,  O_ * H_ / 4);
  vadd<<<16, 256, 0, stream>>>(bih1, bhh1, bsum1, G4_);
  vadd<<<16, 256, 0, stream>>>(bih2, bhh2, bsum2, G4_);
  zero_init<<<256, 256, 0, stream>>>(cst1, cst2, hx1h, hx1l, hx2h, hx2l, bar);

  const dim3 gX(32, 64);
  const dim3 gF(32, 8);

  gemmX<I_, 0, 0><<<gX, 256, 0, stream>>>(
      x, nullptr, nullptr, Wih1_hi, Wih1_lo, bsum1, xp1, G4_, 0);

  unsigned ep = 0;
  for (int c = 0; c <= NCH; ++c){
    const int mode = ((c < NCH) ? 1 : 0) | ((c >= 1) ? 2 : 0);
    const int nwg  = (mode == 3) ? 256 : 128;
    int ngrp = nwg / WPG;
    {
      void* args[] = { (void*)&mode, (void*)&ep, (void*)&ngrp,
                       (void*)&Whh1_hi, (void*)&Whh1_lo, (void*)&xp1, (void*)&cst1,
                       (void*)&hx1h, (void*)&hx1l, (void*)&h1s_hi, (void*)&h1s_lo,
                       (void*)&Whh2_hi, (void*)&Whh2_lo, (void*)&xp2, (void*)&cst2,
                       (void*)&hx2h, (void*)&hx2l, (void*)&h2s_hi, (void*)&h2s_lo,
                       (void*)&bar };
      hipLaunchCooperativeKernel((const void*)lstm_pd, dim3(nwg), dim3(512),
                                 args, 0, stream);
      ep += TC_;
    }
    if (c < NCH)
      gemmX<H_, 1, 0><<<gX, 256, 0, stream>>>(
          nullptr, h1s_hi, h1s_lo, Wih2_hi, Wih2_lo, bsum2, xp2, G4_, 0);
    if (c + 1 < NCH)
      gemmX<I_, 0, 0><<<gX, 256, 0, stream>>>(
          x, nullptr, nullptr, Wih1_hi, Wih1_lo, bsum1, xp1, G4_, (c + 1) * TC_);
    if (c >= 1)
      gemmX<H_, 1, 1><<<gF, 256, 0, stream>>>(
          nullptr, h2s_hi, h2s_lo, fcW_hi, fcW_lo, fcb, out, O_, (c - 1) * TC_);
  }
}